// Round 1
// baseline (1373.714 us; speedup 1.0000x reference)
//
#include <hip/hip_runtime.h>
#include <math.h>

#define NN 50000
#define NE 50000
#define NNZ_E 800000

// ---------------- CSR build ----------------

__global__ void count_kernel(const int* __restrict__ vi, const int* __restrict__ hi,
                             int* __restrict__ cv, int* __restrict__ ce) {
    int k = blockIdx.x * 256 + threadIdx.x;
    if (k < NNZ_E) {
        atomicAdd(&cv[vi[k]], 1);
        atomicAdd(&ce[hi[k]], 1);
    }
}

// Single-block scan over n<=50176 counts -> segment starts (offs), mutable
// cursors (for fill), and 1/max(count,1) as float.
__global__ __launch_bounds__(1024) void scan_kernel(const int* __restrict__ counts,
                                                    int* __restrict__ offs,
                                                    int* __restrict__ cursor,
                                                    float* __restrict__ inv, int n) {
    __shared__ int part[1024];
    int tid = threadIdx.x;
    int chunk = (n + 1023) >> 10;
    int lo = tid * chunk;
    int hi2 = lo + chunk; if (hi2 > n) hi2 = n;
    int s = 0;
    for (int i = lo; i < hi2; i++) s += counts[i];
    part[tid] = s;
    __syncthreads();
    for (int o = 1; o < 1024; o <<= 1) {
        int add = (tid >= o) ? part[tid - o] : 0;
        __syncthreads();
        part[tid] += add;
        __syncthreads();
    }
    int base = (tid > 0) ? part[tid - 1] : 0;
    for (int i = lo; i < hi2; i++) {
        int c = counts[i];
        offs[i] = base;
        cursor[i] = base;
        inv[i] = 1.0f / fmaxf((float)c, 1.0f);
        base += c;
    }
}

__global__ void fill_kernel(const int* __restrict__ vi, const int* __restrict__ hi,
                            int* __restrict__ cur_v, int* __restrict__ cur_e,
                            int* __restrict__ pay_v, int* __restrict__ pay_e) {
    int k = blockIdx.x * 256 + threadIdx.x;
    if (k < NNZ_E) {
        int v = vi[k], e = hi[k];
        pay_e[atomicAdd(&cur_e[e], 1)] = v;  // hedge-major CSR stores node idx
        pay_v[atomicAdd(&cur_v[v], 1)] = e;  // node-major CSR stores hedge idx
    }
}

// ---------------- fp32 GEMM: C[M,N] = A[M,K] @ B[K,N] ----------------
// BM=BN=64, BK=16, 256 threads, 4x4 micro-tile per thread.

#define BM 64
#define BN 64
#define BK 16

__global__ __launch_bounds__(256) void gemm_f32(const float* __restrict__ A,
                                                const float* __restrict__ B,
                                                float* __restrict__ C,
                                                int M, int N, int K) {
    __shared__ float As[BK][BM + 4];  // +4 pad keeps 16B alignment of [k][4*ty]
    __shared__ float Bs[BK][BN];
    int tid = threadIdx.x;
    int row0 = blockIdx.y * BM, col0 = blockIdx.x * BN;
    int tx = tid & 15, ty = tid >> 4;

    // A-load mapping: 256 float4 loads cover 64x16 tile
    int am = tid >> 2, ak = (tid & 3) * 4;
    // B-load mapping: 256 float4 loads cover 16x64 tile
    int bk = tid >> 4, bn = (tid & 15) * 4;

    float acc[4][4] = {};
    for (int k0 = 0; k0 < K; k0 += BK) {
        float4 a4 = make_float4(0.f, 0.f, 0.f, 0.f);
        int arow = row0 + am;
        if (arow < M) a4 = *(const float4*)(A + (size_t)arow * K + k0 + ak);
        As[ak + 0][am] = a4.x; As[ak + 1][am] = a4.y;
        As[ak + 2][am] = a4.z; As[ak + 3][am] = a4.w;
        float4 b4 = *(const float4*)(B + (size_t)(k0 + bk) * N + col0 + bn);
        *(float4*)&Bs[bk][bn] = b4;
        __syncthreads();
#pragma unroll
        for (int kk = 0; kk < BK; kk++) {
            float4 av = *(const float4*)&As[kk][ty * 4];
            float4 bv = *(const float4*)&Bs[kk][tx * 4];
            float a[4] = {av.x, av.y, av.z, av.w};
            float b[4] = {bv.x, bv.y, bv.z, bv.w};
#pragma unroll
            for (int j = 0; j < 4; j++)
#pragma unroll
                for (int i = 0; i < 4; i++) acc[j][i] += a[j] * b[i];
        }
        __syncthreads();
    }
#pragma unroll
    for (int j = 0; j < 4; j++) {
        int r = row0 + ty * 4 + j;
        if (r < M) {
            float4 o = make_float4(acc[j][0], acc[j][1], acc[j][2], acc[j][3]);
            *(float4*)(C + (size_t)r * N + col0 + tx * 4) = o;
        }
    }
}

// ---------------- segment gather-reduce (write-once, fused epilogue) -------
// LPR lanes per output row, each lane owns 4 channels (C = LPR*4).
// dst[row] = act( inv[row] * sum_{j in segment} src[payload[j]] + bias )

template <int LPR>
__global__ __launch_bounds__(256) void seg_reduce(const float* __restrict__ src,
                                                  const int* __restrict__ offs,
                                                  const int* __restrict__ counts,
                                                  const int* __restrict__ payload,
                                                  const float* __restrict__ inv,
                                                  const float* __restrict__ bias,
                                                  float* __restrict__ dst,
                                                  int nrows, int act) {
    const int C = LPR * 4;
    int gtid = blockIdx.x * 256 + threadIdx.x;
    int row = gtid / LPR;
    if (row >= nrows) return;
    int lane = gtid % LPR;
    int c = lane * 4;
    int start = offs[row], cnt = counts[row];
    float4 acc = make_float4(0.f, 0.f, 0.f, 0.f);
    for (int j = 0; j < cnt; j++) {
        int sr = payload[start + j];
        float4 v = *(const float4*)(src + (size_t)sr * C + c);
        acc.x += v.x; acc.y += v.y; acc.z += v.z; acc.w += v.w;
    }
    float s = inv[row];
    acc.x *= s; acc.y *= s; acc.z *= s; acc.w *= s;
    if (bias) {
        acc.x += bias[c + 0]; acc.y += bias[c + 1];
        acc.z += bias[c + 2]; acc.w += bias[c + 3];
    }
    if (act) {  // ELU, alpha=1
        acc.x = acc.x > 0.f ? acc.x : expm1f(acc.x);
        acc.y = acc.y > 0.f ? acc.y : expm1f(acc.y);
        acc.z = acc.z > 0.f ? acc.z : expm1f(acc.z);
        acc.w = acc.w > 0.f ? acc.w : expm1f(acc.w);
    }
    *(float4*)(dst + (size_t)row * C + c) = acc;
}

// ---------------- launch ----------------

extern "C" void kernel_launch(void* const* d_in, const int* in_sizes, int n_in,
                              void* d_out, int out_size, void* d_ws, size_t ws_size,
                              hipStream_t stream) {
    const float* x  = (const float*)d_in[0];
    const int*   ei = (const int*)d_in[1];
    const int* vi = ei;
    const int* hi = ei + NNZ_E;
    // d_in[2] edge_weight unused by reference
    const float* W1 = (const float*)d_in[3];
    const float* b1 = (const float*)d_in[4];
    const float* W2 = (const float*)d_in[5];
    const float* b2 = (const float*)d_in[6];
    const float* W3 = (const float*)d_in[7];
    const float* b3 = (const float*)d_in[8];
    float* out = (float*)d_out;

    char* p = (char*)d_ws;
    auto take = [&](size_t bytes) -> void* {
        void* r = (void*)p;
        p += (bytes + 255) & ~(size_t)255;
        return r;
    };
    int* counts_v = (int*)take(NN * 4);
    int* counts_e = (int*)take(NE * 4);
    int* offs_v   = (int*)take(NN * 4);
    int* offs_e   = (int*)take(NE * 4);
    int* cur_v    = (int*)take(NN * 4);
    int* cur_e    = (int*)take(NE * 4);
    int* pay_v    = (int*)take((size_t)NNZ_E * 4);
    int* pay_e    = (int*)take((size_t)NNZ_E * 4);
    float* inv_v  = (float*)take(NN * 4);
    float* inv_e  = (float*)take(NE * 4);
    float* bufA   = (float*)take((size_t)NN * 256 * 4);
    float* bufB   = (float*)take((size_t)NN * 256 * 4);
    float* bufC   = (float*)take((size_t)NN * 256 * 4);

    hipMemsetAsync(counts_v, 0, NN * 4, stream);
    hipMemsetAsync(counts_e, 0, NE * 4, stream);
    count_kernel<<<(NNZ_E + 255) / 256, 256, 0, stream>>>(vi, hi, counts_v, counts_e);
    scan_kernel<<<1, 1024, 0, stream>>>(counts_v, offs_v, cur_v, inv_v, NN);
    scan_kernel<<<1, 1024, 0, stream>>>(counts_e, offs_e, cur_e, inv_e, NE);
    fill_kernel<<<(NNZ_E + 255) / 256, 256, 0, stream>>>(vi, hi, cur_v, cur_e, pay_v, pay_e);

    dim3 g256(256 / BN, (NN + BM - 1) / BM);
    dim3 g128(128 / BN, (NN + BM - 1) / BM);
    int grid64 = (NN * 64 + 255) / 256;   // seg_reduce C=256
    int grid32 = (NN * 32 + 255) / 256;   // seg_reduce C=128

    // ---- layer 1 ----
    gemm_f32<<<g256, 256, 0, stream>>>(x, W1, bufA, NN, 256, 256);
    seg_reduce<64><<<grid64, 256, 0, stream>>>(bufA, offs_e, counts_e, pay_e, inv_e,
                                               nullptr, bufB, NE, 0);
    seg_reduce<64><<<grid64, 256, 0, stream>>>(bufB, offs_v, counts_v, pay_v, inv_v,
                                               b1, bufC, NN, 1);
    // ---- layer 2 ----
    gemm_f32<<<g256, 256, 0, stream>>>(bufC, W2, bufA, NN, 256, 256);
    seg_reduce<64><<<grid64, 256, 0, stream>>>(bufA, offs_e, counts_e, pay_e, inv_e,
                                               nullptr, bufB, NE, 0);
    seg_reduce<64><<<grid64, 256, 0, stream>>>(bufB, offs_v, counts_v, pay_v, inv_v,
                                               b2, bufC, NN, 1);
    // ---- layer 3 (C=128, no activation) ----
    gemm_f32<<<g128, 256, 0, stream>>>(bufC, W3, bufA, NN, 128, 256);
    seg_reduce<32><<<grid32, 256, 0, stream>>>(bufA, offs_e, counts_e, pay_e, inv_e,
                                               nullptr, bufB, NE, 0);
    seg_reduce<32><<<grid32, 256, 0, stream>>>(bufB, offs_v, counts_v, pay_v, inv_v,
                                               b3, out, NN, 0);
}

// Round 2
// 1161.884 us; speedup vs baseline: 1.1823x; 1.1823x over previous
//
#include <hip/hip_runtime.h>
#include <math.h>

#define NN 50000
#define NE 50000
#define NNZ_E 800000

// ---------------- CSR build ----------------

__global__ void count_kernel(const int* __restrict__ vi, const int* __restrict__ hi,
                             int* __restrict__ cv, int* __restrict__ ce) {
    int k = blockIdx.x * 256 + threadIdx.x;
    if (k < NNZ_E) {
        atomicAdd(&cv[vi[k]], 1);
        atomicAdd(&ce[hi[k]], 1);
    }
}

// Phase A: per-block (256-wide) inclusive scan; emits exclusive value + block sum.
__global__ __launch_bounds__(256) void scan_blk(const int* __restrict__ counts,
                                                int* __restrict__ excl,
                                                int* __restrict__ blocksum, int n) {
    __shared__ int sh[256];
    int tid = threadIdx.x;
    int i = blockIdx.x * 256 + tid;
    int v = (i < n) ? counts[i] : 0;
    sh[tid] = v;
    __syncthreads();
    for (int o = 1; o < 256; o <<= 1) {
        int add = (tid >= o) ? sh[tid - o] : 0;
        __syncthreads();
        sh[tid] += add;
        __syncthreads();
    }
    if (i < n) excl[i] = sh[tid] - v;
    if (tid == 255) blocksum[blockIdx.x] = sh[255];
}

// Phase B: single-block exclusive scan of <=256 block sums.
__global__ __launch_bounds__(256) void scan_top(const int* __restrict__ blocksum,
                                                int* __restrict__ blockbase, int nb) {
    __shared__ int sh[256];
    int tid = threadIdx.x;
    int v = (tid < nb) ? blocksum[tid] : 0;
    sh[tid] = v;
    __syncthreads();
    for (int o = 1; o < 256; o <<= 1) {
        int add = (tid >= o) ? sh[tid - o] : 0;
        __syncthreads();
        sh[tid] += add;
        __syncthreads();
    }
    if (tid < nb) blockbase[tid] = sh[tid] - v;
}

// Phase C: offs/cursor/inv fixup.
__global__ void scan_fix(const int* __restrict__ counts, const int* __restrict__ excl,
                         const int* __restrict__ blockbase, int* __restrict__ offs,
                         int* __restrict__ cursor, float* __restrict__ inv, int n) {
    int i = blockIdx.x * 256 + threadIdx.x;
    if (i < n) {
        int o = excl[i] + blockbase[i >> 8];
        offs[i] = o;
        cursor[i] = o;
        inv[i] = 1.0f / fmaxf((float)counts[i], 1.0f);
    }
}

__global__ void fill_kernel(const int* __restrict__ vi, const int* __restrict__ hi,
                            int* __restrict__ cur_v, int* __restrict__ cur_e,
                            int* __restrict__ pay_v, int* __restrict__ pay_e) {
    int k = blockIdx.x * 256 + threadIdx.x;
    if (k < NNZ_E) {
        int v = vi[k], e = hi[k];
        pay_e[atomicAdd(&cur_e[e], 1)] = v;  // hedge-major CSR stores node idx
        pay_v[atomicAdd(&cur_v[v], 1)] = e;  // node-major CSR stores hedge idx
    }
}

// ---------------- fp32 GEMM: C[M,N] = A[M,K] @ B[K,N] ----------------
// 128x128 tile, BK=16, 256 threads, 8x8 micro-tile split 4+4 (conflict-free LDS reads).

#define TBM 128
#define TBN 128
#define TBK 16

__global__ __launch_bounds__(256) void gemm_f32_128(const float* __restrict__ A,
                                                    const float* __restrict__ B,
                                                    float* __restrict__ C,
                                                    int M, int N, int K) {
    __shared__ float As[TBK][TBM + 4];
    __shared__ float Bs[TBK][TBN];
    int tid = threadIdx.x;
    int tx = tid & 15, ty = tid >> 4;
    int row0 = blockIdx.y * TBM, col0 = blockIdx.x * TBN;

    int am = tid >> 1;           // 0..127
    int ak = (tid & 1) * 8;      // 0 or 8
    int bk = tid >> 4;           // 0..15
    int bn = (tid & 15) * 4;     // 0..60

    float acc[2][2][4][4] = {};

    for (int k0 = 0; k0 < K; k0 += TBK) {
        float4 a40 = make_float4(0.f, 0.f, 0.f, 0.f), a41 = a40;
        int arow = row0 + am;
        if (arow < M) {
            a40 = *(const float4*)(A + (size_t)arow * K + k0 + ak);
            a41 = *(const float4*)(A + (size_t)arow * K + k0 + ak + 4);
        }
        As[ak + 0][am] = a40.x; As[ak + 1][am] = a40.y;
        As[ak + 2][am] = a40.z; As[ak + 3][am] = a40.w;
        As[ak + 4][am] = a41.x; As[ak + 5][am] = a41.y;
        As[ak + 6][am] = a41.z; As[ak + 7][am] = a41.w;
        *(float4*)&Bs[bk][bn]      = *(const float4*)(B + (size_t)(k0 + bk) * N + col0 + bn);
        *(float4*)&Bs[bk][bn + 64] = *(const float4*)(B + (size_t)(k0 + bk) * N + col0 + bn + 64);
        __syncthreads();
#pragma unroll
        for (int kk = 0; kk < TBK; kk++) {
            float a[2][4], b[2][4];
            *(float4*)a[0] = *(const float4*)&As[kk][ty * 4];
            *(float4*)a[1] = *(const float4*)&As[kk][64 + ty * 4];
            *(float4*)b[0] = *(const float4*)&Bs[kk][tx * 4];
            *(float4*)b[1] = *(const float4*)&Bs[kk][64 + tx * 4];
#pragma unroll
            for (int ri = 0; ri < 2; ri++)
#pragma unroll
                for (int ci = 0; ci < 2; ci++)
#pragma unroll
                    for (int r = 0; r < 4; r++)
#pragma unroll
                        for (int c = 0; c < 4; c++)
                            acc[ri][ci][r][c] += a[ri][r] * b[ci][c];
        }
        __syncthreads();
    }
#pragma unroll
    for (int ri = 0; ri < 2; ri++)
#pragma unroll
        for (int r = 0; r < 4; r++) {
            int row = row0 + ri * 64 + ty * 4 + r;
            if (row < M) {
#pragma unroll
                for (int ci = 0; ci < 2; ci++)
                    *(float4*)(C + (size_t)row * N + col0 + ci * 64 + tx * 4) =
                        *(float4*)acc[ri][ci][r];
            }
        }
}

// ---------------- segment gather-reduce (write-once, fused epilogue) -------

template <int LPR>
__global__ __launch_bounds__(256) void seg_reduce(const float* __restrict__ src,
                                                  const int* __restrict__ offs,
                                                  const int* __restrict__ counts,
                                                  const int* __restrict__ payload,
                                                  const float* __restrict__ inv,
                                                  const float* __restrict__ bias,
                                                  float* __restrict__ dst,
                                                  int nrows, int act) {
    const int C = LPR * 4;
    int gtid = blockIdx.x * 256 + threadIdx.x;
    int row = gtid / LPR;
    if (row >= nrows) return;
    int lane = gtid % LPR;
    int c = lane * 4;
    int start = offs[row], cnt = counts[row];
    float4 acc = make_float4(0.f, 0.f, 0.f, 0.f);
    for (int j = 0; j < cnt; j++) {
        int sr = payload[start + j];
        float4 v = *(const float4*)(src + (size_t)sr * C + c);
        acc.x += v.x; acc.y += v.y; acc.z += v.z; acc.w += v.w;
    }
    float s = inv[row];
    acc.x *= s; acc.y *= s; acc.z *= s; acc.w *= s;
    if (bias) {
        acc.x += bias[c + 0]; acc.y += bias[c + 1];
        acc.z += bias[c + 2]; acc.w += bias[c + 3];
    }
    if (act) {  // ELU, alpha=1
        acc.x = acc.x > 0.f ? acc.x : expm1f(acc.x);
        acc.y = acc.y > 0.f ? acc.y : expm1f(acc.y);
        acc.z = acc.z > 0.f ? acc.z : expm1f(acc.z);
        acc.w = acc.w > 0.f ? acc.w : expm1f(acc.w);
    }
    *(float4*)(dst + (size_t)row * C + c) = acc;
}

// ---------------- launch ----------------

extern "C" void kernel_launch(void* const* d_in, const int* in_sizes, int n_in,
                              void* d_out, int out_size, void* d_ws, size_t ws_size,
                              hipStream_t stream) {
    const float* x  = (const float*)d_in[0];
    const int*   ei = (const int*)d_in[1];
    const int* vi = ei;
    const int* hi = ei + NNZ_E;
    const float* W1 = (const float*)d_in[3];
    const float* b1 = (const float*)d_in[4];
    const float* W2 = (const float*)d_in[5];
    const float* b2 = (const float*)d_in[6];
    const float* W3 = (const float*)d_in[7];
    const float* b3 = (const float*)d_in[8];
    float* out = (float*)d_out;

    char* p = (char*)d_ws;
    auto take = [&](size_t bytes) -> void* {
        void* r = (void*)p;
        p += (bytes + 255) & ~(size_t)255;
        return r;
    };
    const int NB = (NN + 255) / 256;  // 196 blocks for both NN and NE
    int* counts_v = (int*)take(NN * 4);
    int* counts_e = (int*)take(NE * 4);
    int* offs_v   = (int*)take(NN * 4);
    int* offs_e   = (int*)take(NE * 4);
    int* cur_v    = (int*)take(NN * 4);
    int* cur_e    = (int*)take(NE * 4);
    int* excl_v   = (int*)take(NN * 4);
    int* excl_e   = (int*)take(NE * 4);
    int* bsum_v   = (int*)take(NB * 4);
    int* bsum_e   = (int*)take(NB * 4);
    int* bbase_v  = (int*)take(NB * 4);
    int* bbase_e  = (int*)take(NB * 4);
    int* pay_v    = (int*)take((size_t)NNZ_E * 4);
    int* pay_e    = (int*)take((size_t)NNZ_E * 4);
    float* inv_v  = (float*)take(NN * 4);
    float* inv_e  = (float*)take(NE * 4);
    float* bufA   = (float*)take((size_t)NN * 256 * 4);
    float* bufB   = (float*)take((size_t)NN * 256 * 4);
    float* bufC   = (float*)take((size_t)NN * 256 * 4);

    hipMemsetAsync(counts_v, 0, NN * 4, stream);
    hipMemsetAsync(counts_e, 0, NE * 4, stream);
    count_kernel<<<(NNZ_E + 255) / 256, 256, 0, stream>>>(vi, hi, counts_v, counts_e);
    scan_blk<<<NB, 256, 0, stream>>>(counts_v, excl_v, bsum_v, NN);
    scan_blk<<<NB, 256, 0, stream>>>(counts_e, excl_e, bsum_e, NE);
    scan_top<<<1, 256, 0, stream>>>(bsum_v, bbase_v, NB);
    scan_top<<<1, 256, 0, stream>>>(bsum_e, bbase_e, NB);
    scan_fix<<<NB, 256, 0, stream>>>(counts_v, excl_v, bbase_v, offs_v, cur_v, inv_v, NN);
    scan_fix<<<NB, 256, 0, stream>>>(counts_e, excl_e, bbase_e, offs_e, cur_e, inv_e, NE);
    fill_kernel<<<(NNZ_E + 255) / 256, 256, 0, stream>>>(vi, hi, cur_v, cur_e, pay_v, pay_e);

    dim3 g256(256 / TBN, (NN + TBM - 1) / TBM);
    dim3 g128(128 / TBN, (NN + TBM - 1) / TBM);
    int grid64 = (NN * 64 + 255) / 256;   // seg_reduce C=256
    int grid32 = (NN * 32 + 255) / 256;   // seg_reduce C=128

    // ---- layer 1 ----
    gemm_f32_128<<<g256, 256, 0, stream>>>(x, W1, bufA, NN, 256, 256);
    seg_reduce<64><<<grid64, 256, 0, stream>>>(bufA, offs_e, counts_e, pay_e, inv_e,
                                               nullptr, bufB, NE, 0);
    seg_reduce<64><<<grid64, 256, 0, stream>>>(bufB, offs_v, counts_v, pay_v, inv_v,
                                               b1, bufC, NN, 1);
    // ---- layer 2 ----
    gemm_f32_128<<<g256, 256, 0, stream>>>(bufC, W2, bufA, NN, 256, 256);
    seg_reduce<64><<<grid64, 256, 0, stream>>>(bufA, offs_e, counts_e, pay_e, inv_e,
                                               nullptr, bufB, NE, 0);
    seg_reduce<64><<<grid64, 256, 0, stream>>>(bufB, offs_v, counts_v, pay_v, inv_v,
                                               b2, bufC, NN, 1);
    // ---- layer 3 (C=128, no activation) ----
    gemm_f32_128<<<g128, 256, 0, stream>>>(bufC, W3, bufA, NN, 128, 256);
    seg_reduce<32><<<grid32, 256, 0, stream>>>(bufA, offs_e, counts_e, pay_e, inv_e,
                                               nullptr, bufB, NE, 0);
    seg_reduce<32><<<grid32, 256, 0, stream>>>(bufB, offs_v, counts_v, pay_v, inv_v,
                                               b3, out, NN, 0);
}

// Round 3
// 1020.625 us; speedup vs baseline: 1.3460x; 1.1384x over previous
//
#include <hip/hip_runtime.h>
#include <math.h>

#define NN 50000
#define NE 50000
#define NNZ_E 800000

typedef _Float16 half_t;
typedef half_t half8 __attribute__((ext_vector_type(8)));
typedef half_t half4v __attribute__((ext_vector_type(4)));
typedef float floatx4 __attribute__((ext_vector_type(4)));

// ---------------- CSR build ----------------

__global__ void count_kernel(const int* __restrict__ vi, const int* __restrict__ hi,
                             int* __restrict__ cv, int* __restrict__ ce) {
    int k = blockIdx.x * 256 + threadIdx.x;
    if (k < NNZ_E) {
        atomicAdd(&cv[vi[k]], 1);
        atomicAdd(&ce[hi[k]], 1);
    }
}

// Phase A: per-block inclusive scan -> exclusive value (into offs) + block sum.
__global__ __launch_bounds__(256) void scan_blk(const int* __restrict__ counts,
                                                int* __restrict__ offs,
                                                int* __restrict__ blocksum, int n) {
    __shared__ int sh[256];
    int tid = threadIdx.x;
    int i = blockIdx.x * 256 + tid;
    int v = (i < n) ? counts[i] : 0;
    sh[tid] = v;
    __syncthreads();
    for (int o = 1; o < 256; o <<= 1) {
        int add = (tid >= o) ? sh[tid - o] : 0;
        __syncthreads();
        sh[tid] += add;
        __syncthreads();
    }
    if (i < n) offs[i] = sh[tid] - v;
    if (tid == 255) blocksum[blockIdx.x] = sh[255];
}

// Phase B: single-block exclusive scan of <=256 block sums.
__global__ __launch_bounds__(256) void scan_top(const int* __restrict__ blocksum,
                                                int* __restrict__ blockbase, int nb) {
    __shared__ int sh[256];
    int tid = threadIdx.x;
    int v = (tid < nb) ? blocksum[tid] : 0;
    sh[tid] = v;
    __syncthreads();
    for (int o = 1; o < 256; o <<= 1) {
        int add = (tid >= o) ? sh[tid - o] : 0;
        __syncthreads();
        sh[tid] += add;
        __syncthreads();
    }
    if (tid < nb) blockbase[tid] = sh[tid] - v;
}

// Phase C: offs (in-place fixup) / cursor / inv.
__global__ void scan_fix(const int* __restrict__ counts, const int* __restrict__ blockbase,
                         int* __restrict__ offs, int* __restrict__ cursor,
                         float* __restrict__ inv, int n) {
    int i = blockIdx.x * 256 + threadIdx.x;
    if (i < n) {
        int o = offs[i] + blockbase[i >> 8];
        offs[i] = o;
        cursor[i] = o;
        inv[i] = 1.0f / fmaxf((float)counts[i], 1.0f);
    }
}

__global__ void fill_kernel(const int* __restrict__ vi, const int* __restrict__ hi,
                            int* __restrict__ cur_v, int* __restrict__ cur_e,
                            int* __restrict__ pay_v, int* __restrict__ pay_e) {
    int k = blockIdx.x * 256 + threadIdx.x;
    if (k < NNZ_E) {
        int v = vi[k], e = hi[k];
        pay_e[atomicAdd(&cur_e[e], 1)] = v;  // hedge-major CSR stores node idx
        pay_v[atomicAdd(&cur_v[v], 1)] = e;  // node-major CSR stores hedge idx
    }
}

// ---------------- fp32 -> (hi,lo) fp16 conversions ----------------

__global__ void cvt_split(const float* __restrict__ X, half_t* __restrict__ Xh,
                          half_t* __restrict__ Xl, int n) {
    int i = (blockIdx.x * 256 + threadIdx.x) * 4;
    if (i < n) {
        float4 v = *(const float4*)(X + i);
        half4v h, l;
        h.x = (half_t)v.x; l.x = (half_t)(v.x - (float)h.x);
        h.y = (half_t)v.y; l.y = (half_t)(v.y - (float)h.y);
        h.z = (half_t)v.z; l.z = (half_t)(v.z - (float)h.z);
        h.w = (half_t)v.w; l.w = (half_t)(v.w - (float)h.w);
        *(half4v*)(Xh + i) = h;
        *(half4v*)(Xl + i) = l;
    }
}

// W [Kd][Nd] fp32 -> transposed hi/lo [Nd][Kd] half.
__global__ void cvt_w(const float* __restrict__ W, half_t* __restrict__ Wth,
                      half_t* __restrict__ Wtl, int Kd, int Nd) {
    int idx = blockIdx.x * 256 + threadIdx.x;
    if (idx < Kd * Nd) {
        int k = idx / Nd, n = idx - k * Nd;
        float v = W[idx];
        half_t h = (half_t)v;
        Wth[(size_t)n * Kd + k] = h;
        Wtl[(size_t)n * Kd + k] = (half_t)(v - (float)h);
    }
}

// ---------------- split-fp16 MFMA GEMM ----------------
// C[M,N] = (Ah+Al)[M,K] @ (Bh+Bl)^T[N,K], fp32 out.
// 128x128 tile, BK=32, 256 threads (4 waves, each a 64x64 quadrant of 4x4
// 16x16x32 MFMA tiles). LDS row stride 40 halves (80B): 2-way bank alias = free.

#define LSTR 40

__global__ __launch_bounds__(256) void gemm_hsplit(const half_t* __restrict__ Ah,
                                                   const half_t* __restrict__ Al,
                                                   const half_t* __restrict__ Bh,
                                                   const half_t* __restrict__ Bl,
                                                   float* __restrict__ C,
                                                   int M, int N, int K) {
    __shared__ __attribute__((aligned(16))) half_t sAh[128 * LSTR];
    __shared__ __attribute__((aligned(16))) half_t sAl[128 * LSTR];
    __shared__ __attribute__((aligned(16))) half_t sBh[128 * LSTR];
    __shared__ __attribute__((aligned(16))) half_t sBl[128 * LSTR];

    int tid = threadIdx.x;
    int wave = tid >> 6, lane = tid & 63;
    int row0 = blockIdx.y * 128, col0 = blockIdx.x * 128;
    int qm = (wave >> 1) * 64, qn = (wave & 1) * 64;

    // staging: thread t covers row sr, 16-half k-chunk sk
    int sr = tid >> 1;
    int sk = (tid & 1) * 16;

    // fragment addressing (16x16x32 f16: lane holds [m=lane&15][k=(lane>>4)*8+j])
    int fm = lane & 15;
    int fk = (lane >> 4) * 8;

    floatx4 acc[4][4] = {};

    for (int k0 = 0; k0 < K; k0 += 32) {
        half8 a0 = {}, a1 = {}, l0 = {}, l1 = {};
        int arow = row0 + sr;
        if (arow < M) {
            const half_t* pa = Ah + (size_t)arow * K + k0 + sk;
            const half_t* pl = Al + (size_t)arow * K + k0 + sk;
            a0 = *(const half8*)pa; a1 = *(const half8*)(pa + 8);
            l0 = *(const half8*)pl; l1 = *(const half8*)(pl + 8);
        }
        *(half8*)&sAh[sr * LSTR + sk]     = a0;
        *(half8*)&sAh[sr * LSTR + sk + 8] = a1;
        *(half8*)&sAl[sr * LSTR + sk]     = l0;
        *(half8*)&sAl[sr * LSTR + sk + 8] = l1;
        {
            const half_t* pb = Bh + (size_t)(col0 + sr) * K + k0 + sk;
            const half_t* pc = Bl + (size_t)(col0 + sr) * K + k0 + sk;
            half8 b0 = *(const half8*)pb, b1 = *(const half8*)(pb + 8);
            half8 c0 = *(const half8*)pc, c1 = *(const half8*)(pc + 8);
            *(half8*)&sBh[sr * LSTR + sk]     = b0;
            *(half8*)&sBh[sr * LSTR + sk + 8] = b1;
            *(half8*)&sBl[sr * LSTR + sk]     = c0;
            *(half8*)&sBl[sr * LSTR + sk + 8] = c1;
        }
        __syncthreads();

        half8 fa_h[4], fa_l[4], fb_h[4], fb_l[4];
#pragma unroll
        for (int i = 0; i < 4; i++) {
            fa_h[i] = *(const half8*)&sAh[(qm + i * 16 + fm) * LSTR + fk];
            fa_l[i] = *(const half8*)&sAl[(qm + i * 16 + fm) * LSTR + fk];
            fb_h[i] = *(const half8*)&sBh[(qn + i * 16 + fm) * LSTR + fk];
            fb_l[i] = *(const half8*)&sBl[(qn + i * 16 + fm) * LSTR + fk];
        }
#pragma unroll
        for (int mi = 0; mi < 4; mi++)
#pragma unroll
            for (int ni = 0; ni < 4; ni++) {
                acc[mi][ni] = __builtin_amdgcn_mfma_f32_16x16x32_f16(fa_h[mi], fb_h[ni], acc[mi][ni], 0, 0, 0);
                acc[mi][ni] = __builtin_amdgcn_mfma_f32_16x16x32_f16(fa_h[mi], fb_l[ni], acc[mi][ni], 0, 0, 0);
                acc[mi][ni] = __builtin_amdgcn_mfma_f32_16x16x32_f16(fa_l[mi], fb_h[ni], acc[mi][ni], 0, 0, 0);
            }
        __syncthreads();
    }

    // epilogue: C/D layout col=lane&15, row=(lane>>4)*4+r
    int er = (lane >> 4) * 4;
    int ec = lane & 15;
#pragma unroll
    for (int mi = 0; mi < 4; mi++)
#pragma unroll
        for (int r = 0; r < 4; r++) {
            int grow = row0 + qm + mi * 16 + er + r;
            if (grow < M) {
#pragma unroll
                for (int ni = 0; ni < 4; ni++)
                    C[(size_t)grow * N + col0 + qn + ni * 16 + ec] = acc[mi][ni][r];
            }
        }
}

// ---------------- segment gather-reduce (write-once, fused epilogue) -------
// If dsth != nullptr: write hi/lo fp16 split pair (A operand for next GEMM);
// else write fp32 dst.

template <int LPR>
__global__ __launch_bounds__(256) void seg_reduce(const float* __restrict__ src,
                                                  const int* __restrict__ offs,
                                                  const int* __restrict__ counts,
                                                  const int* __restrict__ payload,
                                                  const float* __restrict__ inv,
                                                  const float* __restrict__ bias,
                                                  float* __restrict__ dst,
                                                  half_t* __restrict__ dsth,
                                                  half_t* __restrict__ dstl,
                                                  int nrows, int act) {
    const int C = LPR * 4;
    int gtid = blockIdx.x * 256 + threadIdx.x;
    int row = gtid / LPR;
    if (row >= nrows) return;
    int lane = gtid % LPR;
    int c = lane * 4;
    int start = offs[row], cnt = counts[row];
    float4 acc = make_float4(0.f, 0.f, 0.f, 0.f);
    for (int j = 0; j < cnt; j++) {
        int sr = payload[start + j];
        float4 v = *(const float4*)(src + (size_t)sr * C + c);
        acc.x += v.x; acc.y += v.y; acc.z += v.z; acc.w += v.w;
    }
    float s = inv[row];
    acc.x *= s; acc.y *= s; acc.z *= s; acc.w *= s;
    if (bias) {
        acc.x += bias[c + 0]; acc.y += bias[c + 1];
        acc.z += bias[c + 2]; acc.w += bias[c + 3];
    }
    if (act) {  // ELU, alpha=1
        acc.x = acc.x > 0.f ? acc.x : expm1f(acc.x);
        acc.y = acc.y > 0.f ? acc.y : expm1f(acc.y);
        acc.z = acc.z > 0.f ? acc.z : expm1f(acc.z);
        acc.w = acc.w > 0.f ? acc.w : expm1f(acc.w);
    }
    if (dsth) {
        half4v h, l;
        h.x = (half_t)acc.x; l.x = (half_t)(acc.x - (float)h.x);
        h.y = (half_t)acc.y; l.y = (half_t)(acc.y - (float)h.y);
        h.z = (half_t)acc.z; l.z = (half_t)(acc.z - (float)h.z);
        h.w = (half_t)acc.w; l.w = (half_t)(acc.w - (float)h.w);
        *(half4v*)(dsth + (size_t)row * C + c) = h;
        *(half4v*)(dstl + (size_t)row * C + c) = l;
    } else {
        *(float4*)(dst + (size_t)row * C + c) = acc;
    }
}

// ---------------- launch ----------------

extern "C" void kernel_launch(void* const* d_in, const int* in_sizes, int n_in,
                              void* d_out, int out_size, void* d_ws, size_t ws_size,
                              hipStream_t stream) {
    const float* x  = (const float*)d_in[0];
    const int*   ei = (const int*)d_in[1];
    const int* vi = ei;
    const int* hi = ei + NNZ_E;
    const float* W1 = (const float*)d_in[3];
    const float* b1 = (const float*)d_in[4];
    const float* W2 = (const float*)d_in[5];
    const float* b2 = (const float*)d_in[6];
    const float* W3 = (const float*)d_in[7];
    const float* b3 = (const float*)d_in[8];
    float* out = (float*)d_out;

    char* p = (char*)d_ws;
    auto take = [&](size_t bytes) -> void* {
        void* r = (void*)p;
        p += (bytes + 255) & ~(size_t)255;
        return r;
    };
    const int NB = (NN + 255) / 256;
    int* counts_v = (int*)take(NN * 4);
    int* counts_e = (int*)take(NE * 4);
    int* offs_v   = (int*)take(NN * 4);
    int* offs_e   = (int*)take(NE * 4);
    int* cur_v    = (int*)take(NN * 4);
    int* cur_e    = (int*)take(NE * 4);
    int* bsum_v   = (int*)take(NB * 4);
    int* bsum_e   = (int*)take(NB * 4);
    int* bbase_v  = (int*)take(NB * 4);
    int* bbase_e  = (int*)take(NB * 4);
    int* pay_v    = (int*)take((size_t)NNZ_E * 4);
    int* pay_e    = (int*)take((size_t)NNZ_E * 4);
    float* inv_v  = (float*)take(NN * 4);
    float* inv_e  = (float*)take(NE * 4);
    float* bufA   = (float*)take((size_t)NN * 256 * 4);   // GEMM out
    float* bufB   = (float*)take((size_t)NN * 256 * 4);   // seg_e out
    half_t* hA_h  = (half_t*)take((size_t)NN * 256 * 2);  // A operand hi
    half_t* hA_l  = (half_t*)take((size_t)NN * 256 * 2);  // A operand lo
    half_t* w1h   = (half_t*)take(256 * 256 * 2);
    half_t* w1l   = (half_t*)take(256 * 256 * 2);
    half_t* w2h   = (half_t*)take(256 * 256 * 2);
    half_t* w2l   = (half_t*)take(256 * 256 * 2);
    half_t* w3h   = (half_t*)take(256 * 128 * 2);
    half_t* w3l   = (half_t*)take(256 * 128 * 2);

    // ---- CSR build ----
    hipMemsetAsync(counts_v, 0, NN * 4, stream);
    hipMemsetAsync(counts_e, 0, NE * 4, stream);
    count_kernel<<<(NNZ_E + 255) / 256, 256, 0, stream>>>(vi, hi, counts_v, counts_e);
    scan_blk<<<NB, 256, 0, stream>>>(counts_v, offs_v, bsum_v, NN);
    scan_blk<<<NB, 256, 0, stream>>>(counts_e, offs_e, bsum_e, NE);
    scan_top<<<1, 256, 0, stream>>>(bsum_v, bbase_v, NB);
    scan_top<<<1, 256, 0, stream>>>(bsum_e, bbase_e, NB);
    scan_fix<<<NB, 256, 0, stream>>>(counts_v, bbase_v, offs_v, cur_v, inv_v, NN);
    scan_fix<<<NB, 256, 0, stream>>>(counts_e, bbase_e, offs_e, cur_e, inv_e, NE);
    fill_kernel<<<(NNZ_E + 255) / 256, 256, 0, stream>>>(vi, hi, cur_v, cur_e, pay_v, pay_e);

    // ---- conversions ----
    cvt_split<<<(NN * 256 / 4 + 255) / 256, 256, 0, stream>>>(x, hA_h, hA_l, NN * 256);
    cvt_w<<<(256 * 256 + 255) / 256, 256, 0, stream>>>(W1, w1h, w1l, 256, 256);
    cvt_w<<<(256 * 256 + 255) / 256, 256, 0, stream>>>(W2, w2h, w2l, 256, 256);
    cvt_w<<<(256 * 128 + 255) / 256, 256, 0, stream>>>(W3, w3h, w3l, 256, 128);

    dim3 g256(2, (NN + 127) / 128);
    dim3 g128(1, (NN + 127) / 128);
    int grid64 = (NN * 64 + 255) / 256;
    int grid32 = (NN * 32 + 255) / 256;

    // ---- layer 1 ----
    gemm_hsplit<<<g256, 256, 0, stream>>>(hA_h, hA_l, w1h, w1l, bufA, NN, 256, 256);
    seg_reduce<64><<<grid64, 256, 0, stream>>>(bufA, offs_e, counts_e, pay_e, inv_e,
                                               nullptr, bufB, nullptr, nullptr, NE, 0);
    seg_reduce<64><<<grid64, 256, 0, stream>>>(bufB, offs_v, counts_v, pay_v, inv_v,
                                               b1, nullptr, hA_h, hA_l, NN, 1);
    // ---- layer 2 ----
    gemm_hsplit<<<g256, 256, 0, stream>>>(hA_h, hA_l, w2h, w2l, bufA, NN, 256, 256);
    seg_reduce<64><<<grid64, 256, 0, stream>>>(bufA, offs_e, counts_e, pay_e, inv_e,
                                               nullptr, bufB, nullptr, nullptr, NE, 0);
    seg_reduce<64><<<grid64, 256, 0, stream>>>(bufB, offs_v, counts_v, pay_v, inv_v,
                                               b2, nullptr, hA_h, hA_l, NN, 1);
    // ---- layer 3 (N=128, no activation) ----
    gemm_hsplit<<<g128, 256, 0, stream>>>(hA_h, hA_l, w3h, w3l, bufA, NN, 128, 256);
    seg_reduce<32><<<grid32, 256, 0, stream>>>(bufA, offs_e, counts_e, pay_e, inv_e,
                                               nullptr, bufB, nullptr, nullptr, NE, 0);
    seg_reduce<32><<<grid32, 256, 0, stream>>>(bufB, offs_v, counts_v, pay_v, inv_v,
                                               b3, out, nullptr, nullptr, NN, 0);
}

// Round 4
// 773.407 us; speedup vs baseline: 1.7762x; 1.3196x over previous
//
#include <hip/hip_runtime.h>
#include <math.h>

#define NN 50000
#define NE 50000
#define NNZ_E 800000

typedef _Float16 half_t;
typedef half_t half8 __attribute__((ext_vector_type(8)));
typedef half_t half4v __attribute__((ext_vector_type(4)));
typedef float floatx4 __attribute__((ext_vector_type(4)));
typedef float floatx8 __attribute__((ext_vector_type(8)));

// ---------------- CSR build ----------------

__global__ void count_kernel(const int* __restrict__ vi, const int* __restrict__ hi,
                             int* __restrict__ cv, int* __restrict__ ce) {
    int k = blockIdx.x * 256 + threadIdx.x;
    if (k < NNZ_E) {
        atomicAdd(&cv[vi[k]], 1);
        atomicAdd(&ce[hi[k]], 1);
    }
}

__global__ __launch_bounds__(256) void scan_blk(const int* __restrict__ counts,
                                                int* __restrict__ offs,
                                                int* __restrict__ blocksum, int n) {
    __shared__ int sh[256];
    int tid = threadIdx.x;
    int i = blockIdx.x * 256 + tid;
    int v = (i < n) ? counts[i] : 0;
    sh[tid] = v;
    __syncthreads();
    for (int o = 1; o < 256; o <<= 1) {
        int add = (tid >= o) ? sh[tid - o] : 0;
        __syncthreads();
        sh[tid] += add;
        __syncthreads();
    }
    if (i < n) offs[i] = sh[tid] - v;
    if (tid == 255) blocksum[blockIdx.x] = sh[255];
}

__global__ __launch_bounds__(256) void scan_top(const int* __restrict__ blocksum,
                                                int* __restrict__ blockbase, int nb) {
    __shared__ int sh[256];
    int tid = threadIdx.x;
    int v = (tid < nb) ? blocksum[tid] : 0;
    sh[tid] = v;
    __syncthreads();
    for (int o = 1; o < 256; o <<= 1) {
        int add = (tid >= o) ? sh[tid - o] : 0;
        __syncthreads();
        sh[tid] += add;
        __syncthreads();
    }
    if (tid < nb) blockbase[tid] = sh[tid] - v;
}

__global__ void scan_fix(const int* __restrict__ counts, const int* __restrict__ blockbase,
                         int* __restrict__ offs, int* __restrict__ cursor,
                         float* __restrict__ inv, int n) {
    int i = blockIdx.x * 256 + threadIdx.x;
    if (i < n) {
        int o = offs[i] + blockbase[i >> 8];
        offs[i] = o;
        cursor[i] = o;
        inv[i] = 1.0f / fmaxf((float)counts[i], 1.0f);
    }
}

__global__ void fill_kernel(const int* __restrict__ vi, const int* __restrict__ hi,
                            int* __restrict__ cur_v, int* __restrict__ cur_e,
                            int* __restrict__ pay_v, int* __restrict__ pay_e) {
    int k = blockIdx.x * 256 + threadIdx.x;
    if (k < NNZ_E) {
        int v = vi[k], e = hi[k];
        pay_e[atomicAdd(&cur_e[e], 1)] = v;
        pay_v[atomicAdd(&cur_v[v], 1)] = e;
    }
}

// ---------------- fp32 -> (hi,lo) fp16 conversions ----------------

__global__ void cvt_split(const float* __restrict__ X, half_t* __restrict__ Xh,
                          half_t* __restrict__ Xl, int n) {
    int i = (blockIdx.x * 256 + threadIdx.x) * 4;
    if (i < n) {
        float4 v = *(const float4*)(X + i);
        half4v h, l;
        h.x = (half_t)v.x; l.x = (half_t)(v.x - (float)h.x);
        h.y = (half_t)v.y; l.y = (half_t)(v.y - (float)h.y);
        h.z = (half_t)v.z; l.z = (half_t)(v.z - (float)h.z);
        h.w = (half_t)v.w; l.w = (half_t)(v.w - (float)h.w);
        *(half4v*)(Xh + i) = h;
        *(half4v*)(Xl + i) = l;
    }
}

__global__ void cvt_w(const float* __restrict__ W, half_t* __restrict__ Wth,
                      half_t* __restrict__ Wtl, int Kd, int Nd) {
    int idx = blockIdx.x * 256 + threadIdx.x;
    if (idx < Kd * Nd) {
        int k = idx / Nd, n = idx - k * Nd;
        float v = W[idx];
        half_t h = (half_t)v;
        Wth[(size_t)n * Kd + k] = h;
        Wtl[(size_t)n * Kd + k] = (half_t)(v - (float)h);
    }
}

// ---------------- split-fp16 MFMA GEMM, fp16 output ----------------
// C[M,N] = (Ah+Al)[M,K] @ (Bh+Bl)^T[N,K]; output rounded once to fp16.

#define LSTR 40

__global__ __launch_bounds__(256) void gemm_hsplit(const half_t* __restrict__ Ah,
                                                   const half_t* __restrict__ Al,
                                                   const half_t* __restrict__ Bh,
                                                   const half_t* __restrict__ Bl,
                                                   half_t* __restrict__ C,
                                                   int M, int N, int K) {
    __shared__ __attribute__((aligned(16))) half_t sAh[128 * LSTR];
    __shared__ __attribute__((aligned(16))) half_t sAl[128 * LSTR];
    __shared__ __attribute__((aligned(16))) half_t sBh[128 * LSTR];
    __shared__ __attribute__((aligned(16))) half_t sBl[128 * LSTR];

    int tid = threadIdx.x;
    int wave = tid >> 6, lane = tid & 63;
    int row0 = blockIdx.y * 128, col0 = blockIdx.x * 128;
    int qm = (wave >> 1) * 64, qn = (wave & 1) * 64;

    int sr = tid >> 1;
    int sk = (tid & 1) * 16;
    int fm = lane & 15;
    int fk = (lane >> 4) * 8;

    floatx4 acc[4][4] = {};

    for (int k0 = 0; k0 < K; k0 += 32) {
        half8 a0 = {}, a1 = {}, l0 = {}, l1 = {};
        int arow = row0 + sr;
        if (arow < M) {
            const half_t* pa = Ah + (size_t)arow * K + k0 + sk;
            const half_t* pl = Al + (size_t)arow * K + k0 + sk;
            a0 = *(const half8*)pa; a1 = *(const half8*)(pa + 8);
            l0 = *(const half8*)pl; l1 = *(const half8*)(pl + 8);
        }
        *(half8*)&sAh[sr * LSTR + sk]     = a0;
        *(half8*)&sAh[sr * LSTR + sk + 8] = a1;
        *(half8*)&sAl[sr * LSTR + sk]     = l0;
        *(half8*)&sAl[sr * LSTR + sk + 8] = l1;
        {
            const half_t* pb = Bh + (size_t)(col0 + sr) * K + k0 + sk;
            const half_t* pc = Bl + (size_t)(col0 + sr) * K + k0 + sk;
            half8 b0 = *(const half8*)pb, b1 = *(const half8*)(pb + 8);
            half8 c0 = *(const half8*)pc, c1 = *(const half8*)(pc + 8);
            *(half8*)&sBh[sr * LSTR + sk]     = b0;
            *(half8*)&sBh[sr * LSTR + sk + 8] = b1;
            *(half8*)&sBl[sr * LSTR + sk]     = c0;
            *(half8*)&sBl[sr * LSTR + sk + 8] = c1;
        }
        __syncthreads();

        half8 fa_h[4], fa_l[4], fb_h[4], fb_l[4];
#pragma unroll
        for (int i = 0; i < 4; i++) {
            fa_h[i] = *(const half8*)&sAh[(qm + i * 16 + fm) * LSTR + fk];
            fa_l[i] = *(const half8*)&sAl[(qm + i * 16 + fm) * LSTR + fk];
            fb_h[i] = *(const half8*)&sBh[(qn + i * 16 + fm) * LSTR + fk];
            fb_l[i] = *(const half8*)&sBl[(qn + i * 16 + fm) * LSTR + fk];
        }
#pragma unroll
        for (int mi = 0; mi < 4; mi++)
#pragma unroll
            for (int ni = 0; ni < 4; ni++) {
                acc[mi][ni] = __builtin_amdgcn_mfma_f32_16x16x32_f16(fa_h[mi], fb_h[ni], acc[mi][ni], 0, 0, 0);
                acc[mi][ni] = __builtin_amdgcn_mfma_f32_16x16x32_f16(fa_h[mi], fb_l[ni], acc[mi][ni], 0, 0, 0);
                acc[mi][ni] = __builtin_amdgcn_mfma_f32_16x16x32_f16(fa_l[mi], fb_h[ni], acc[mi][ni], 0, 0, 0);
            }
        __syncthreads();
    }

    int er = (lane >> 4) * 4;
    int ec = lane & 15;
#pragma unroll
    for (int mi = 0; mi < 4; mi++)
#pragma unroll
        for (int r = 0; r < 4; r++) {
            int grow = row0 + qm + mi * 16 + er + r;
            if (grow < M) {
#pragma unroll
                for (int ni = 0; ni < 4; ni++)
                    C[(size_t)grow * N + col0 + qn + ni * 16 + ec] = (half_t)acc[mi][ni][r];
            }
        }
}

// ---------------- fp16 segment gather-reduce, fp32 accumulate --------------
// LPR lanes per row, 8 channels (half8 = 16B) per lane. C = LPR*8.
// MODE 0: dst_h = fp16(inv*sum)                       (xe, no bias/act)
// MODE 1: dst_h/dst_l = split(ELU(inv*sum + bias))    (xv, next GEMM A)
// MODE 2: dst_f = inv*sum + bias                      (final output)

template <int LPR, int MODE>
__global__ __launch_bounds__(256) void seg16(const half_t* __restrict__ src,
                                             const int* __restrict__ offs,
                                             const int* __restrict__ counts,
                                             const int* __restrict__ payload,
                                             const float* __restrict__ inv,
                                             const float* __restrict__ bias,
                                             half_t* __restrict__ dst_h,
                                             half_t* __restrict__ dst_l,
                                             float* __restrict__ dst_f,
                                             int nrows) {
    const int C = LPR * 8;
    int gtid = blockIdx.x * 256 + threadIdx.x;
    int row = gtid / LPR;
    if (row >= nrows) return;
    int c0 = (gtid % LPR) * 8;
    int start = offs[row], cnt = counts[row];
    floatx8 acc = {};
    for (int j = 0; j < cnt; j++) {
        int sr = payload[start + j];
        half8 v = *(const half8*)(src + (size_t)sr * C + c0);
        acc += __builtin_convertvector(v, floatx8);
    }
    acc *= inv[row];
    if (MODE >= 1) {
        float4 b0 = *(const float4*)(bias + c0);
        float4 b1 = *(const float4*)(bias + c0 + 4);
        acc[0] += b0.x; acc[1] += b0.y; acc[2] += b0.z; acc[3] += b0.w;
        acc[4] += b1.x; acc[5] += b1.y; acc[6] += b1.z; acc[7] += b1.w;
    }
    if (MODE == 1) {  // ELU then full-precision fp16 split
#pragma unroll
        for (int j = 0; j < 8; j++) acc[j] = acc[j] > 0.f ? acc[j] : expm1f(acc[j]);
        half8 h = __builtin_convertvector(acc, half8);
        floatx8 back = __builtin_convertvector(h, floatx8);
        half8 l = __builtin_convertvector(acc - back, half8);
        *(half8*)(dst_h + (size_t)row * C + c0) = h;
        *(half8*)(dst_l + (size_t)row * C + c0) = l;
    } else if (MODE == 0) {
        *(half8*)(dst_h + (size_t)row * C + c0) = __builtin_convertvector(acc, half8);
    } else {
        float* o = dst_f + (size_t)row * C + c0;
        *(float4*)o = make_float4(acc[0], acc[1], acc[2], acc[3]);
        *(float4*)(o + 4) = make_float4(acc[4], acc[5], acc[6], acc[7]);
    }
}

// ---------------- launch ----------------

extern "C" void kernel_launch(void* const* d_in, const int* in_sizes, int n_in,
                              void* d_out, int out_size, void* d_ws, size_t ws_size,
                              hipStream_t stream) {
    const float* x  = (const float*)d_in[0];
    const int*   ei = (const int*)d_in[1];
    const int* vi = ei;
    const int* hi = ei + NNZ_E;
    const float* W1 = (const float*)d_in[3];
    const float* b1 = (const float*)d_in[4];
    const float* W2 = (const float*)d_in[5];
    const float* b2 = (const float*)d_in[6];
    const float* W3 = (const float*)d_in[7];
    const float* b3 = (const float*)d_in[8];
    float* out = (float*)d_out;

    char* p = (char*)d_ws;
    auto take = [&](size_t bytes) -> void* {
        void* r = (void*)p;
        p += (bytes + 255) & ~(size_t)255;
        return r;
    };
    const int NB = (NN + 255) / 256;
    int* counts_v = (int*)take(NN * 4);
    int* counts_e = (int*)take(NE * 4);
    int* offs_v   = (int*)take(NN * 4);
    int* offs_e   = (int*)take(NE * 4);
    int* cur_v    = (int*)take(NN * 4);
    int* cur_e    = (int*)take(NE * 4);
    int* bsum_v   = (int*)take(NB * 4);
    int* bsum_e   = (int*)take(NB * 4);
    int* bbase_v  = (int*)take(NB * 4);
    int* bbase_e  = (int*)take(NB * 4);
    int* pay_v    = (int*)take((size_t)NNZ_E * 4);
    int* pay_e    = (int*)take((size_t)NNZ_E * 4);
    float* inv_v  = (float*)take(NN * 4);
    float* inv_e  = (float*)take(NE * 4);
    half_t* msgH  = (half_t*)take((size_t)NN * 256 * 2);  // GEMM out (fp16)
    half_t* xeH   = (half_t*)take((size_t)NE * 256 * 2);  // seg_e out (fp16)
    half_t* hA_h  = (half_t*)take((size_t)NN * 256 * 2);  // GEMM A hi
    half_t* hA_l  = (half_t*)take((size_t)NN * 256 * 2);  // GEMM A lo
    half_t* w1h   = (half_t*)take(256 * 256 * 2);
    half_t* w1l   = (half_t*)take(256 * 256 * 2);
    half_t* w2h   = (half_t*)take(256 * 256 * 2);
    half_t* w2l   = (half_t*)take(256 * 256 * 2);
    half_t* w3h   = (half_t*)take(256 * 128 * 2);
    half_t* w3l   = (half_t*)take(256 * 128 * 2);

    // ---- CSR build ----
    hipMemsetAsync(counts_v, 0, NN * 4, stream);
    hipMemsetAsync(counts_e, 0, NE * 4, stream);
    count_kernel<<<(NNZ_E + 255) / 256, 256, 0, stream>>>(vi, hi, counts_v, counts_e);
    scan_blk<<<NB, 256, 0, stream>>>(counts_v, offs_v, bsum_v, NN);
    scan_blk<<<NB, 256, 0, stream>>>(counts_e, offs_e, bsum_e, NE);
    scan_top<<<1, 256, 0, stream>>>(bsum_v, bbase_v, NB);
    scan_top<<<1, 256, 0, stream>>>(bsum_e, bbase_e, NB);
    scan_fix<<<NB, 256, 0, stream>>>(counts_v, bbase_v, offs_v, cur_v, inv_v, NN);
    scan_fix<<<NB, 256, 0, stream>>>(counts_e, bbase_e, offs_e, cur_e, inv_e, NE);
    fill_kernel<<<(NNZ_E + 255) / 256, 256, 0, stream>>>(vi, hi, cur_v, cur_e, pay_v, pay_e);

    // ---- conversions ----
    cvt_split<<<(NN * 256 / 4 + 255) / 256, 256, 0, stream>>>(x, hA_h, hA_l, NN * 256);
    cvt_w<<<(256 * 256 + 255) / 256, 256, 0, stream>>>(W1, w1h, w1l, 256, 256);
    cvt_w<<<(256 * 256 + 255) / 256, 256, 0, stream>>>(W2, w2h, w2l, 256, 256);
    cvt_w<<<(256 * 128 + 255) / 256, 256, 0, stream>>>(W3, w3h, w3l, 256, 128);

    dim3 g256(2, (NN + 127) / 128);
    dim3 g128(1, (NN + 127) / 128);
    int gridC256 = (NN * 32 + 255) / 256;  // LPR=32
    int gridC128 = (NN * 16 + 255) / 256;  // LPR=16

    // ---- layer 1 ----
    gemm_hsplit<<<g256, 256, 0, stream>>>(hA_h, hA_l, w1h, w1l, msgH, NN, 256, 256);
    seg16<32, 0><<<gridC256, 256, 0, stream>>>(msgH, offs_e, counts_e, pay_e, inv_e,
                                               nullptr, xeH, nullptr, nullptr, NE);
    seg16<32, 1><<<gridC256, 256, 0, stream>>>(xeH, offs_v, counts_v, pay_v, inv_v,
                                               b1, hA_h, hA_l, nullptr, NN);
    // ---- layer 2 ----
    gemm_hsplit<<<g256, 256, 0, stream>>>(hA_h, hA_l, w2h, w2l, msgH, NN, 256, 256);
    seg16<32, 0><<<gridC256, 256, 0, stream>>>(msgH, offs_e, counts_e, pay_e, inv_e,
                                               nullptr, xeH, nullptr, nullptr, NE);
    seg16<32, 1><<<gridC256, 256, 0, stream>>>(xeH, offs_v, counts_v, pay_v, inv_v,
                                               b2, hA_h, hA_l, nullptr, NN);
    // ---- layer 3 (C=128, no activation) ----
    gemm_hsplit<<<g128, 256, 0, stream>>>(hA_h, hA_l, w3h, w3l, msgH, NN, 128, 256);
    seg16<16, 0><<<gridC128, 256, 0, stream>>>(msgH, offs_e, counts_e, pay_e, inv_e,
                                               nullptr, xeH, nullptr, nullptr, NE);
    seg16<16, 2><<<gridC128, 256, 0, stream>>>(xeH, offs_v, counts_v, pay_v, inv_v,
                                               b3, nullptr, nullptr, out, NN);
}

// Round 5
// 629.669 us; speedup vs baseline: 2.1816x; 1.2283x over previous
//
#include <hip/hip_runtime.h>
#include <math.h>

#define NN 50000
#define NE 50000
#define NNZ_E 800000
#define NBUCK 196   // buckets = seg >> 8, segs < 50176
#define BCAP 8192   // per-bucket capacity (avg fill 4082, 60+ sigma headroom)
#define EPB 2048    // edges per bin block

typedef _Float16 half_t;
typedef half_t half8 __attribute__((ext_vector_type(8)));
typedef half_t half4v __attribute__((ext_vector_type(4)));
typedef float floatx4 __attribute__((ext_vector_type(4)));
typedef float floatx8 __attribute__((ext_vector_type(8)));

// ---------------- CSR build: bucket binning ----------------
// Record: (val << 8) | (seg & 255); val < 2^17, fits 25 bits.

__global__ __launch_bounds__(256) void bin_kernel(const int* __restrict__ vi,
                                                  const int* __restrict__ hi,
                                                  int* __restrict__ bcur_e,
                                                  int* __restrict__ bcur_v,
                                                  unsigned int* __restrict__ tmp_e,
                                                  unsigned int* __restrict__ tmp_v) {
    __shared__ int cnt_e[NBUCK], cnt_v[NBUCK];
    __shared__ int gb_e[NBUCK], gb_v[NBUCK];
    int tid = threadIdx.x;
    for (int i = tid; i < NBUCK; i += 256) { cnt_e[i] = 0; cnt_v[i] = 0; }
    __syncthreads();
    int base = blockIdx.x * EPB;
    int nE = NNZ_E - base; if (nE > EPB) nE = EPB;
    int v[8], e[8], re[8], rv[8];
#pragma unroll
    for (int i = 0; i < 8; i++) {
        int off = i * 256 + tid;
        if (off < nE) {
            int k = base + off;
            v[i] = vi[k]; e[i] = hi[k];
            re[i] = atomicAdd(&cnt_e[e[i] >> 8], 1);
            rv[i] = atomicAdd(&cnt_v[v[i] >> 8], 1);
        }
    }
    __syncthreads();
    for (int i = tid; i < NBUCK; i += 256) {
        if (cnt_e[i] > 0) gb_e[i] = atomicAdd(&bcur_e[i], cnt_e[i]);
        if (cnt_v[i] > 0) gb_v[i] = atomicAdd(&bcur_v[i], cnt_v[i]);
    }
    __syncthreads();
#pragma unroll
    for (int i = 0; i < 8; i++) {
        int off = i * 256 + tid;
        if (off < nE) {
            int be = e[i] >> 8, bv = v[i] >> 8;
            tmp_e[(size_t)be * BCAP + gb_e[be] + re[i]] = ((unsigned)v[i] << 8) | (e[i] & 255);
            tmp_v[(size_t)bv * BCAP + gb_v[bv] + rv[i]] = ((unsigned)e[i] << 8) | (v[i] & 255);
        }
    }
}

// One block per bucket: histogram records -> per-segment counts (coalesced).
__global__ __launch_bounds__(256) void fine_count(const int* __restrict__ bcur,
                                                  const unsigned int* __restrict__ tmp,
                                                  int* __restrict__ counts, int nseg) {
    __shared__ int h[256];
    int b = blockIdx.x, tid = threadIdx.x;
    h[tid] = 0;
    __syncthreads();
    int n = bcur[b];
    const unsigned int* t = tmp + (size_t)b * BCAP;
    for (int i = tid; i < n; i += 256) atomicAdd(&h[t[i] & 255], 1);
    __syncthreads();
    int seg = b * 256 + tid;
    if (seg < nseg) counts[seg] = h[tid];
}

// One block per bucket: scatter vals into payload window (L2-resident, exclusive).
__global__ __launch_bounds__(256) void fine_scatter(const int* __restrict__ bcur,
                                                    const unsigned int* __restrict__ tmp,
                                                    const int* __restrict__ offs,
                                                    int* __restrict__ payload, int nseg) {
    __shared__ int cur[256];
    int b = blockIdx.x, tid = threadIdx.x;
    int seg = b * 256 + tid;
    cur[tid] = (seg < nseg) ? offs[seg] : 0;
    __syncthreads();
    int n = bcur[b];
    const unsigned int* t = tmp + (size_t)b * BCAP;
    for (int i = tid; i < n; i += 256) {
        unsigned int r = t[i];
        int pos = atomicAdd(&cur[r & 255], 1);
        payload[pos] = r >> 8;
    }
}

// ---------------- scan (3-phase) ----------------

__global__ __launch_bounds__(256) void scan_blk(const int* __restrict__ counts,
                                                int* __restrict__ offs,
                                                int* __restrict__ blocksum, int n) {
    __shared__ int sh[256];
    int tid = threadIdx.x;
    int i = blockIdx.x * 256 + tid;
    int v = (i < n) ? counts[i] : 0;
    sh[tid] = v;
    __syncthreads();
    for (int o = 1; o < 256; o <<= 1) {
        int add = (tid >= o) ? sh[tid - o] : 0;
        __syncthreads();
        sh[tid] += add;
        __syncthreads();
    }
    if (i < n) offs[i] = sh[tid] - v;
    if (tid == 255) blocksum[blockIdx.x] = sh[255];
}

__global__ __launch_bounds__(256) void scan_top(const int* __restrict__ blocksum,
                                                int* __restrict__ blockbase, int nb) {
    __shared__ int sh[256];
    int tid = threadIdx.x;
    int v = (tid < nb) ? blocksum[tid] : 0;
    sh[tid] = v;
    __syncthreads();
    for (int o = 1; o < 256; o <<= 1) {
        int add = (tid >= o) ? sh[tid - o] : 0;
        __syncthreads();
        sh[tid] += add;
        __syncthreads();
    }
    if (tid < nb) blockbase[tid] = sh[tid] - v;
}

__global__ void scan_fix(const int* __restrict__ counts, const int* __restrict__ blockbase,
                         int* __restrict__ offs, float* __restrict__ inv, int n) {
    int i = blockIdx.x * 256 + threadIdx.x;
    if (i < n) {
        offs[i] = offs[i] + blockbase[i >> 8];
        inv[i] = 1.0f / fmaxf((float)counts[i], 1.0f);
    }
}

// ---------------- fp32 -> (hi,lo) fp16 conversions ----------------

__global__ void cvt_split(const float* __restrict__ X, half_t* __restrict__ Xh,
                          half_t* __restrict__ Xl, int n) {
    int i = (blockIdx.x * 256 + threadIdx.x) * 4;
    if (i < n) {
        float4 v = *(const float4*)(X + i);
        half4v h, l;
        h.x = (half_t)v.x; l.x = (half_t)(v.x - (float)h.x);
        h.y = (half_t)v.y; l.y = (half_t)(v.y - (float)h.y);
        h.z = (half_t)v.z; l.z = (half_t)(v.z - (float)h.z);
        h.w = (half_t)v.w; l.w = (half_t)(v.w - (float)h.w);
        *(half4v*)(Xh + i) = h;
        *(half4v*)(Xl + i) = l;
    }
}

__global__ void cvt_w(const float* __restrict__ W, half_t* __restrict__ Wth,
                      half_t* __restrict__ Wtl, int Kd, int Nd) {
    int idx = blockIdx.x * 256 + threadIdx.x;
    if (idx < Kd * Nd) {
        int k = idx / Nd, n = idx - k * Nd;
        float v = W[idx];
        half_t h = (half_t)v;
        Wth[(size_t)n * Kd + k] = h;
        Wtl[(size_t)n * Kd + k] = (half_t)(v - (float)h);
    }
}

// ---------------- split-fp16 MFMA GEMM, fp16 output ----------------

#define LSTR 40

__global__ __launch_bounds__(256) void gemm_hsplit(const half_t* __restrict__ Ah,
                                                   const half_t* __restrict__ Al,
                                                   const half_t* __restrict__ Bh,
                                                   const half_t* __restrict__ Bl,
                                                   half_t* __restrict__ C,
                                                   int M, int N, int K) {
    __shared__ __attribute__((aligned(16))) half_t sAh[128 * LSTR];
    __shared__ __attribute__((aligned(16))) half_t sAl[128 * LSTR];
    __shared__ __attribute__((aligned(16))) half_t sBh[128 * LSTR];
    __shared__ __attribute__((aligned(16))) half_t sBl[128 * LSTR];

    int tid = threadIdx.x;
    int wave = tid >> 6, lane = tid & 63;
    int row0 = blockIdx.y * 128, col0 = blockIdx.x * 128;
    int qm = (wave >> 1) * 64, qn = (wave & 1) * 64;

    int sr = tid >> 1;
    int sk = (tid & 1) * 16;
    int fm = lane & 15;
    int fk = (lane >> 4) * 8;

    floatx4 acc[4][4] = {};

    for (int k0 = 0; k0 < K; k0 += 32) {
        half8 a0 = {}, a1 = {}, l0 = {}, l1 = {};
        int arow = row0 + sr;
        if (arow < M) {
            const half_t* pa = Ah + (size_t)arow * K + k0 + sk;
            const half_t* pl = Al + (size_t)arow * K + k0 + sk;
            a0 = *(const half8*)pa; a1 = *(const half8*)(pa + 8);
            l0 = *(const half8*)pl; l1 = *(const half8*)(pl + 8);
        }
        *(half8*)&sAh[sr * LSTR + sk]     = a0;
        *(half8*)&sAh[sr * LSTR + sk + 8] = a1;
        *(half8*)&sAl[sr * LSTR + sk]     = l0;
        *(half8*)&sAl[sr * LSTR + sk + 8] = l1;
        {
            const half_t* pb = Bh + (size_t)(col0 + sr) * K + k0 + sk;
            const half_t* pc = Bl + (size_t)(col0 + sr) * K + k0 + sk;
            half8 b0 = *(const half8*)pb, b1 = *(const half8*)(pb + 8);
            half8 c0 = *(const half8*)pc, c1 = *(const half8*)(pc + 8);
            *(half8*)&sBh[sr * LSTR + sk]     = b0;
            *(half8*)&sBh[sr * LSTR + sk + 8] = b1;
            *(half8*)&sBl[sr * LSTR + sk]     = c0;
            *(half8*)&sBl[sr * LSTR + sk + 8] = c1;
        }
        __syncthreads();

        half8 fa_h[4], fa_l[4], fb_h[4], fb_l[4];
#pragma unroll
        for (int i = 0; i < 4; i++) {
            fa_h[i] = *(const half8*)&sAh[(qm + i * 16 + fm) * LSTR + fk];
            fa_l[i] = *(const half8*)&sAl[(qm + i * 16 + fm) * LSTR + fk];
            fb_h[i] = *(const half8*)&sBh[(qn + i * 16 + fm) * LSTR + fk];
            fb_l[i] = *(const half8*)&sBl[(qn + i * 16 + fm) * LSTR + fk];
        }
#pragma unroll
        for (int mi = 0; mi < 4; mi++)
#pragma unroll
            for (int ni = 0; ni < 4; ni++) {
                acc[mi][ni] = __builtin_amdgcn_mfma_f32_16x16x32_f16(fa_h[mi], fb_h[ni], acc[mi][ni], 0, 0, 0);
                acc[mi][ni] = __builtin_amdgcn_mfma_f32_16x16x32_f16(fa_h[mi], fb_l[ni], acc[mi][ni], 0, 0, 0);
                acc[mi][ni] = __builtin_amdgcn_mfma_f32_16x16x32_f16(fa_l[mi], fb_h[ni], acc[mi][ni], 0, 0, 0);
            }
        __syncthreads();
    }

    int er = (lane >> 4) * 4;
    int ec = lane & 15;
#pragma unroll
    for (int mi = 0; mi < 4; mi++)
#pragma unroll
        for (int r = 0; r < 4; r++) {
            int grow = row0 + qm + mi * 16 + er + r;
            if (grow < M) {
#pragma unroll
                for (int ni = 0; ni < 4; ni++)
                    C[(size_t)grow * N + col0 + qn + ni * 16 + ec] = (half_t)acc[mi][ni][r];
            }
        }
}

// ---------------- fp16 segment gather-reduce, fp32 accumulate --------------
// MODE 0: dst_h = fp16(inv*sum); MODE 1: split(ELU(inv*sum+bias)); MODE 2: fp32 out.

template <int LPR, int MODE>
__global__ __launch_bounds__(256) void seg16(const half_t* __restrict__ src,
                                             const int* __restrict__ offs,
                                             const int* __restrict__ counts,
                                             const int* __restrict__ payload,
                                             const float* __restrict__ inv,
                                             const float* __restrict__ bias,
                                             half_t* __restrict__ dst_h,
                                             half_t* __restrict__ dst_l,
                                             float* __restrict__ dst_f,
                                             int nrows) {
    const int C = LPR * 8;
    int gtid = blockIdx.x * 256 + threadIdx.x;
    int row = gtid / LPR;
    if (row >= nrows) return;
    int c0 = (gtid % LPR) * 8;
    int start = offs[row], cnt = counts[row];
    floatx8 acc = {};
    for (int j = 0; j < cnt; j++) {
        int sr = payload[start + j];
        half8 v = *(const half8*)(src + (size_t)sr * C + c0);
        acc += __builtin_convertvector(v, floatx8);
    }
    acc *= inv[row];
    if (MODE >= 1) {
        float4 b0 = *(const float4*)(bias + c0);
        float4 b1 = *(const float4*)(bias + c0 + 4);
        acc[0] += b0.x; acc[1] += b0.y; acc[2] += b0.z; acc[3] += b0.w;
        acc[4] += b1.x; acc[5] += b1.y; acc[6] += b1.z; acc[7] += b1.w;
    }
    if (MODE == 1) {
#pragma unroll
        for (int j = 0; j < 8; j++) acc[j] = acc[j] > 0.f ? acc[j] : expm1f(acc[j]);
        half8 h = __builtin_convertvector(acc, half8);
        floatx8 back = __builtin_convertvector(h, floatx8);
        half8 l = __builtin_convertvector(acc - back, half8);
        *(half8*)(dst_h + (size_t)row * C + c0) = h;
        *(half8*)(dst_l + (size_t)row * C + c0) = l;
    } else if (MODE == 0) {
        *(half8*)(dst_h + (size_t)row * C + c0) = __builtin_convertvector(acc, half8);
    } else {
        float* o = dst_f + (size_t)row * C + c0;
        *(float4*)o = make_float4(acc[0], acc[1], acc[2], acc[3]);
        *(float4*)(o + 4) = make_float4(acc[4], acc[5], acc[6], acc[7]);
    }
}

// ---------------- launch ----------------

extern "C" void kernel_launch(void* const* d_in, const int* in_sizes, int n_in,
                              void* d_out, int out_size, void* d_ws, size_t ws_size,
                              hipStream_t stream) {
    const float* x  = (const float*)d_in[0];
    const int*   ei = (const int*)d_in[1];
    const int* vi = ei;
    const int* hi = ei + NNZ_E;
    const float* W1 = (const float*)d_in[3];
    const float* b1 = (const float*)d_in[4];
    const float* W2 = (const float*)d_in[5];
    const float* b2 = (const float*)d_in[6];
    const float* W3 = (const float*)d_in[7];
    const float* b3 = (const float*)d_in[8];
    float* out = (float*)d_out;

    char* p = (char*)d_ws;
    auto take = [&](size_t bytes) -> void* {
        void* r = (void*)p;
        p += (bytes + 255) & ~(size_t)255;
        return r;
    };
    const int NB = (NN + 255) / 256;
    int* counts_v = (int*)take(NN * 4);
    int* counts_e = (int*)take(NE * 4);
    int* offs_v   = (int*)take(NN * 4);
    int* offs_e   = (int*)take(NE * 4);
    int* bsum_v   = (int*)take(NB * 4);
    int* bsum_e   = (int*)take(NB * 4);
    int* bbase_v  = (int*)take(NB * 4);
    int* bbase_e  = (int*)take(NB * 4);
    int* bcur_e   = (int*)take(NBUCK * 4);
    int* bcur_v   = (int*)take(NBUCK * 4);
    unsigned int* tmp_e = (unsigned int*)take((size_t)NBUCK * BCAP * 4);
    unsigned int* tmp_v = (unsigned int*)take((size_t)NBUCK * BCAP * 4);
    int* pay_v    = (int*)take((size_t)NNZ_E * 4);
    int* pay_e    = (int*)take((size_t)NNZ_E * 4);
    float* inv_v  = (float*)take(NN * 4);
    float* inv_e  = (float*)take(NE * 4);
    half_t* msgH  = (half_t*)take((size_t)NN * 256 * 2);
    half_t* xeH   = (half_t*)take((size_t)NE * 256 * 2);
    half_t* hA_h  = (half_t*)take((size_t)NN * 256 * 2);
    half_t* hA_l  = (half_t*)take((size_t)NN * 256 * 2);
    half_t* w1h   = (half_t*)take(256 * 256 * 2);
    half_t* w1l   = (half_t*)take(256 * 256 * 2);
    half_t* w2h   = (half_t*)take(256 * 256 * 2);
    half_t* w2l   = (half_t*)take(256 * 256 * 2);
    half_t* w3h   = (half_t*)take(256 * 128 * 2);
    half_t* w3l   = (half_t*)take(256 * 128 * 2);

    // ---- CSR build (bucket-binned, no random global scatter) ----
    hipMemsetAsync(bcur_e, 0, NBUCK * 4, stream);
    hipMemsetAsync(bcur_v, 0, NBUCK * 4, stream);
    bin_kernel<<<(NNZ_E + EPB - 1) / EPB, 256, 0, stream>>>(vi, hi, bcur_e, bcur_v, tmp_e, tmp_v);
    fine_count<<<NBUCK, 256, 0, stream>>>(bcur_e, tmp_e, counts_e, NE);
    fine_count<<<NBUCK, 256, 0, stream>>>(bcur_v, tmp_v, counts_v, NN);
    scan_blk<<<NB, 256, 0, stream>>>(counts_v, offs_v, bsum_v, NN);
    scan_blk<<<NB, 256, 0, stream>>>(counts_e, offs_e, bsum_e, NE);
    scan_top<<<1, 256, 0, stream>>>(bsum_v, bbase_v, NB);
    scan_top<<<1, 256, 0, stream>>>(bsum_e, bbase_e, NB);
    scan_fix<<<NB, 256, 0, stream>>>(counts_v, bbase_v, offs_v, inv_v, NN);
    scan_fix<<<NB, 256, 0, stream>>>(counts_e, bbase_e, offs_e, inv_e, NE);
    fine_scatter<<<NBUCK, 256, 0, stream>>>(bcur_e, tmp_e, offs_e, pay_e, NE);
    fine_scatter<<<NBUCK, 256, 0, stream>>>(bcur_v, tmp_v, offs_v, pay_v, NN);

    // ---- conversions ----
    cvt_split<<<(NN * 256 / 4 + 255) / 256, 256, 0, stream>>>(x, hA_h, hA_l, NN * 256);
    cvt_w<<<(256 * 256 + 255) / 256, 256, 0, stream>>>(W1, w1h, w1l, 256, 256);
    cvt_w<<<(256 * 256 + 255) / 256, 256, 0, stream>>>(W2, w2h, w2l, 256, 256);
    cvt_w<<<(256 * 128 + 255) / 256, 256, 0, stream>>>(W3, w3h, w3l, 256, 128);

    dim3 g256(2, (NN + 127) / 128);
    dim3 g128(1, (NN + 127) / 128);
    int gridC256 = (NN * 32 + 255) / 256;  // LPR=32
    int gridC128 = (NN * 16 + 255) / 256;  // LPR=16

    // ---- layer 1 ----
    gemm_hsplit<<<g256, 256, 0, stream>>>(hA_h, hA_l, w1h, w1l, msgH, NN, 256, 256);
    seg16<32, 0><<<gridC256, 256, 0, stream>>>(msgH, offs_e, counts_e, pay_e, inv_e,
                                               nullptr, xeH, nullptr, nullptr, NE);
    seg16<32, 1><<<gridC256, 256, 0, stream>>>(xeH, offs_v, counts_v, pay_v, inv_v,
                                               b1, hA_h, hA_l, nullptr, NN);
    // ---- layer 2 ----
    gemm_hsplit<<<g256, 256, 0, stream>>>(hA_h, hA_l, w2h, w2l, msgH, NN, 256, 256);
    seg16<32, 0><<<gridC256, 256, 0, stream>>>(msgH, offs_e, counts_e, pay_e, inv_e,
                                               nullptr, xeH, nullptr, nullptr, NE);
    seg16<32, 1><<<gridC256, 256, 0, stream>>>(xeH, offs_v, counts_v, pay_v, inv_v,
                                               b2, hA_h, hA_l, nullptr, NN);
    // ---- layer 3 (C=128, no activation) ----
    gemm_hsplit<<<g128, 256, 0, stream>>>(hA_h, hA_l, w3h, w3l, msgH, NN, 128, 256);
    seg16<16, 0><<<gridC128, 256, 0, stream>>>(msgH, offs_e, counts_e, pay_e, inv_e,
                                               nullptr, xeH, nullptr, nullptr, NE);
    seg16<16, 2><<<gridC128, 256, 0, stream>>>(xeH, offs_v, counts_v, pay_v, inv_v,
                                               b3, nullptr, nullptr, out, NN);
}

// Round 6
// 576.472 us; speedup vs baseline: 2.3830x; 1.0923x over previous
//
#include <hip/hip_runtime.h>
#include <math.h>

#define NN 50000
#define NE 50000
#define NNZ_E 800000
#define NBUCK 196   // buckets = seg >> 8, segs < 50176
#define BCAP 8192   // per-bucket capacity (avg fill 4082, 60+ sigma headroom)
#define EPB 2048    // edges per bin block

typedef _Float16 half_t;
typedef half_t half8 __attribute__((ext_vector_type(8)));
typedef half_t half4v __attribute__((ext_vector_type(4)));
typedef float floatx4 __attribute__((ext_vector_type(4)));
typedef float floatx8 __attribute__((ext_vector_type(8)));

// ---------------- CSR build: bucket binning ----------------
// Record: (val << 8) | (seg & 255); val < 2^17, fits 25 bits.

__global__ __launch_bounds__(256) void bin_kernel(const int* __restrict__ vi,
                                                  const int* __restrict__ hi,
                                                  int* __restrict__ bcur_e,
                                                  int* __restrict__ bcur_v,
                                                  unsigned int* __restrict__ tmp_e,
                                                  unsigned int* __restrict__ tmp_v) {
    __shared__ int cnt_e[NBUCK], cnt_v[NBUCK];
    __shared__ int gb_e[NBUCK], gb_v[NBUCK];
    int tid = threadIdx.x;
    for (int i = tid; i < NBUCK; i += 256) { cnt_e[i] = 0; cnt_v[i] = 0; }
    __syncthreads();
    int base = blockIdx.x * EPB;
    int nE = NNZ_E - base; if (nE > EPB) nE = EPB;
    int v[8], e[8], re[8], rv[8];
#pragma unroll
    for (int i = 0; i < 8; i++) {
        int off = i * 256 + tid;
        if (off < nE) {
            int k = base + off;
            v[i] = vi[k]; e[i] = hi[k];
            re[i] = atomicAdd(&cnt_e[e[i] >> 8], 1);
            rv[i] = atomicAdd(&cnt_v[v[i] >> 8], 1);
        }
    }
    __syncthreads();
    for (int i = tid; i < NBUCK; i += 256) {
        if (cnt_e[i] > 0) gb_e[i] = atomicAdd(&bcur_e[i], cnt_e[i]);
        if (cnt_v[i] > 0) gb_v[i] = atomicAdd(&bcur_v[i], cnt_v[i]);
    }
    __syncthreads();
#pragma unroll
    for (int i = 0; i < 8; i++) {
        int off = i * 256 + tid;
        if (off < nE) {
            int be = e[i] >> 8, bv = v[i] >> 8;
            tmp_e[(size_t)be * BCAP + gb_e[be] + re[i]] = ((unsigned)v[i] << 8) | (e[i] & 255);
            tmp_v[(size_t)bv * BCAP + gb_v[bv] + rv[i]] = ((unsigned)e[i] << 8) | (v[i] & 255);
        }
    }
}

// One block per bucket: histogram records -> per-segment counts (coalesced).
__global__ __launch_bounds__(256) void fine_count(const int* __restrict__ bcur,
                                                  const unsigned int* __restrict__ tmp,
                                                  int* __restrict__ counts, int nseg) {
    __shared__ int h[256];
    int b = blockIdx.x, tid = threadIdx.x;
    h[tid] = 0;
    __syncthreads();
    int n = bcur[b];
    const unsigned int* t = tmp + (size_t)b * BCAP;
    for (int i = tid; i < n; i += 256) atomicAdd(&h[t[i] & 255], 1);
    __syncthreads();
    int seg = b * 256 + tid;
    if (seg < nseg) counts[seg] = h[tid];
}

// One block per bucket: scatter vals into payload window (L2-resident, exclusive).
__global__ __launch_bounds__(256) void fine_scatter(const int* __restrict__ bcur,
                                                    const unsigned int* __restrict__ tmp,
                                                    const int* __restrict__ offs,
                                                    int* __restrict__ payload, int nseg) {
    __shared__ int cur[256];
    int b = blockIdx.x, tid = threadIdx.x;
    int seg = b * 256 + tid;
    cur[tid] = (seg < nseg) ? offs[seg] : 0;
    __syncthreads();
    int n = bcur[b];
    const unsigned int* t = tmp + (size_t)b * BCAP;
    for (int i = tid; i < n; i += 256) {
        unsigned int r = t[i];
        int pos = atomicAdd(&cur[r & 255], 1);
        payload[pos] = r >> 8;
    }
}

// ---------------- scan (3-phase) ----------------

__global__ __launch_bounds__(256) void scan_blk(const int* __restrict__ counts,
                                                int* __restrict__ offs,
                                                int* __restrict__ blocksum, int n) {
    __shared__ int sh[256];
    int tid = threadIdx.x;
    int i = blockIdx.x * 256 + tid;
    int v = (i < n) ? counts[i] : 0;
    sh[tid] = v;
    __syncthreads();
    for (int o = 1; o < 256; o <<= 1) {
        int add = (tid >= o) ? sh[tid - o] : 0;
        __syncthreads();
        sh[tid] += add;
        __syncthreads();
    }
    if (i < n) offs[i] = sh[tid] - v;
    if (tid == 255) blocksum[blockIdx.x] = sh[255];
}

__global__ __launch_bounds__(256) void scan_top(const int* __restrict__ blocksum,
                                                int* __restrict__ blockbase, int nb) {
    __shared__ int sh[256];
    int tid = threadIdx.x;
    int v = (tid < nb) ? blocksum[tid] : 0;
    sh[tid] = v;
    __syncthreads();
    for (int o = 1; o < 256; o <<= 1) {
        int add = (tid >= o) ? sh[tid - o] : 0;
        __syncthreads();
        sh[tid] += add;
        __syncthreads();
    }
    if (tid < nb) blockbase[tid] = sh[tid] - v;
}

__global__ void scan_fix(const int* __restrict__ counts, const int* __restrict__ blockbase,
                         int* __restrict__ offs, float* __restrict__ inv, int n) {
    int i = blockIdx.x * 256 + threadIdx.x;
    if (i < n) {
        offs[i] = offs[i] + blockbase[i >> 8];
        inv[i] = 1.0f / fmaxf((float)counts[i], 1.0f);
    }
}

// ---------------- fp32 -> (hi,lo) fp16 conversions ----------------

__global__ void cvt_split(const float* __restrict__ X, half_t* __restrict__ Xh,
                          half_t* __restrict__ Xl, int n) {
    int i = (blockIdx.x * 256 + threadIdx.x) * 4;
    if (i < n) {
        float4 v = *(const float4*)(X + i);
        half4v h, l;
        h.x = (half_t)v.x; l.x = (half_t)(v.x - (float)h.x);
        h.y = (half_t)v.y; l.y = (half_t)(v.y - (float)h.y);
        h.z = (half_t)v.z; l.z = (half_t)(v.z - (float)h.z);
        h.w = (half_t)v.w; l.w = (half_t)(v.w - (float)h.w);
        *(half4v*)(Xh + i) = h;
        *(half4v*)(Xl + i) = l;
    }
}

__global__ void cvt_w(const float* __restrict__ W, half_t* __restrict__ Wth,
                      half_t* __restrict__ Wtl, int Kd, int Nd) {
    int idx = blockIdx.x * 256 + threadIdx.x;
    if (idx < Kd * Nd) {
        int k = idx / Nd, n = idx - k * Nd;
        float v = W[idx];
        half_t h = (half_t)v;
        Wth[(size_t)n * Kd + k] = h;
        Wtl[(size_t)n * Kd + k] = (half_t)(v - (float)h);
    }
}

// ---------------- split-fp16 MFMA GEMM, fp16 output ----------------

#define LSTR 40

__global__ __launch_bounds__(256) void gemm_hsplit(const half_t* __restrict__ Ah,
                                                   const half_t* __restrict__ Al,
                                                   const half_t* __restrict__ Bh,
                                                   const half_t* __restrict__ Bl,
                                                   half_t* __restrict__ C,
                                                   int M, int N, int K) {
    __shared__ __attribute__((aligned(16))) half_t sAh[128 * LSTR];
    __shared__ __attribute__((aligned(16))) half_t sAl[128 * LSTR];
    __shared__ __attribute__((aligned(16))) half_t sBh[128 * LSTR];
    __shared__ __attribute__((aligned(16))) half_t sBl[128 * LSTR];

    int tid = threadIdx.x;
    int wave = tid >> 6, lane = tid & 63;
    int row0 = blockIdx.y * 128, col0 = blockIdx.x * 128;
    int qm = (wave >> 1) * 64, qn = (wave & 1) * 64;

    int sr = tid >> 1;
    int sk = (tid & 1) * 16;
    int fm = lane & 15;
    int fk = (lane >> 4) * 8;

    floatx4 acc[4][4] = {};

    for (int k0 = 0; k0 < K; k0 += 32) {
        half8 a0 = {}, a1 = {}, l0 = {}, l1 = {};
        int arow = row0 + sr;
        if (arow < M) {
            const half_t* pa = Ah + (size_t)arow * K + k0 + sk;
            const half_t* pl = Al + (size_t)arow * K + k0 + sk;
            a0 = *(const half8*)pa; a1 = *(const half8*)(pa + 8);
            l0 = *(const half8*)pl; l1 = *(const half8*)(pl + 8);
        }
        *(half8*)&sAh[sr * LSTR + sk]     = a0;
        *(half8*)&sAh[sr * LSTR + sk + 8] = a1;
        *(half8*)&sAl[sr * LSTR + sk]     = l0;
        *(half8*)&sAl[sr * LSTR + sk + 8] = l1;
        {
            const half_t* pb = Bh + (size_t)(col0 + sr) * K + k0 + sk;
            const half_t* pc = Bl + (size_t)(col0 + sr) * K + k0 + sk;
            half8 b0 = *(const half8*)pb, b1 = *(const half8*)(pb + 8);
            half8 c0 = *(const half8*)pc, c1 = *(const half8*)(pc + 8);
            *(half8*)&sBh[sr * LSTR + sk]     = b0;
            *(half8*)&sBh[sr * LSTR + sk + 8] = b1;
            *(half8*)&sBl[sr * LSTR + sk]     = c0;
            *(half8*)&sBl[sr * LSTR + sk + 8] = c1;
        }
        __syncthreads();

        half8 fa_h[4], fa_l[4], fb_h[4], fb_l[4];
#pragma unroll
        for (int i = 0; i < 4; i++) {
            fa_h[i] = *(const half8*)&sAh[(qm + i * 16 + fm) * LSTR + fk];
            fa_l[i] = *(const half8*)&sAl[(qm + i * 16 + fm) * LSTR + fk];
            fb_h[i] = *(const half8*)&sBh[(qn + i * 16 + fm) * LSTR + fk];
            fb_l[i] = *(const half8*)&sBl[(qn + i * 16 + fm) * LSTR + fk];
        }
#pragma unroll
        for (int mi = 0; mi < 4; mi++)
#pragma unroll
            for (int ni = 0; ni < 4; ni++) {
                acc[mi][ni] = __builtin_amdgcn_mfma_f32_16x16x32_f16(fa_h[mi], fb_h[ni], acc[mi][ni], 0, 0, 0);
                acc[mi][ni] = __builtin_amdgcn_mfma_f32_16x16x32_f16(fa_h[mi], fb_l[ni], acc[mi][ni], 0, 0, 0);
                acc[mi][ni] = __builtin_amdgcn_mfma_f32_16x16x32_f16(fa_l[mi], fb_h[ni], acc[mi][ni], 0, 0, 0);
            }
        __syncthreads();
    }

    int er = (lane >> 4) * 4;
    int ec = lane & 15;
#pragma unroll
    for (int mi = 0; mi < 4; mi++)
#pragma unroll
        for (int r = 0; r < 4; r++) {
            int grow = row0 + qm + mi * 16 + er + r;
            if (grow < M) {
#pragma unroll
                for (int ni = 0; ni < 4; ni++)
                    C[(size_t)grow * N + col0 + qn + ni * 16 + ec] = (half_t)acc[mi][ni][r];
            }
        }
}

// ---------------- fp16 segment gather-reduce, fp32 accumulate --------------
// 4-deep unrolled gather: 4 independent row-loads in flight per lane (MLP).
// MODE 0: dst_h = fp16(inv*sum); MODE 1: split(ELU(inv*sum+bias)); MODE 2: fp32 out.

template <int LPR, int MODE>
__global__ __launch_bounds__(256) void seg16(const half_t* __restrict__ src,
                                             const int* __restrict__ offs,
                                             const int* __restrict__ counts,
                                             const int* __restrict__ payload,
                                             const float* __restrict__ inv,
                                             const float* __restrict__ bias,
                                             half_t* __restrict__ dst_h,
                                             half_t* __restrict__ dst_l,
                                             float* __restrict__ dst_f,
                                             int nrows) {
    const int C = LPR * 8;
    int gtid = blockIdx.x * 256 + threadIdx.x;
    int row = gtid / LPR;
    if (row >= nrows) return;
    int c0 = (gtid % LPR) * 8;
    int start = offs[row], cnt = counts[row];
    int j = start, end = start + cnt;
    floatx8 a0 = {}, a1 = {}, a2 = {}, a3 = {};
    for (; j + 4 <= end; j += 4) {
        int s0 = payload[j], s1 = payload[j + 1], s2 = payload[j + 2], s3 = payload[j + 3];
        half8 v0 = *(const half8*)(src + (size_t)s0 * C + c0);
        half8 v1 = *(const half8*)(src + (size_t)s1 * C + c0);
        half8 v2 = *(const half8*)(src + (size_t)s2 * C + c0);
        half8 v3 = *(const half8*)(src + (size_t)s3 * C + c0);
        a0 += __builtin_convertvector(v0, floatx8);
        a1 += __builtin_convertvector(v1, floatx8);
        a2 += __builtin_convertvector(v2, floatx8);
        a3 += __builtin_convertvector(v3, floatx8);
    }
    for (; j < end; j++) {
        int sr = payload[j];
        half8 v = *(const half8*)(src + (size_t)sr * C + c0);
        a0 += __builtin_convertvector(v, floatx8);
    }
    floatx8 acc = (a0 + a1) + (a2 + a3);
    acc *= inv[row];
    if (MODE >= 1) {
        float4 b0 = *(const float4*)(bias + c0);
        float4 b1 = *(const float4*)(bias + c0 + 4);
        acc[0] += b0.x; acc[1] += b0.y; acc[2] += b0.z; acc[3] += b0.w;
        acc[4] += b1.x; acc[5] += b1.y; acc[6] += b1.z; acc[7] += b1.w;
    }
    if (MODE == 1) {
#pragma unroll
        for (int k = 0; k < 8; k++) acc[k] = acc[k] > 0.f ? acc[k] : expm1f(acc[k]);
        half8 h = __builtin_convertvector(acc, half8);
        floatx8 back = __builtin_convertvector(h, floatx8);
        half8 l = __builtin_convertvector(acc - back, half8);
        *(half8*)(dst_h + (size_t)row * C + c0) = h;
        *(half8*)(dst_l + (size_t)row * C + c0) = l;
    } else if (MODE == 0) {
        *(half8*)(dst_h + (size_t)row * C + c0) = __builtin_convertvector(acc, half8);
    } else {
        float* o = dst_f + (size_t)row * C + c0;
        *(float4*)o = make_float4(acc[0], acc[1], acc[2], acc[3]);
        *(float4*)(o + 4) = make_float4(acc[4], acc[5], acc[6], acc[7]);
    }
}

// ---------------- launch ----------------

extern "C" void kernel_launch(void* const* d_in, const int* in_sizes, int n_in,
                              void* d_out, int out_size, void* d_ws, size_t ws_size,
                              hipStream_t stream) {
    const float* x  = (const float*)d_in[0];
    const int*   ei = (const int*)d_in[1];
    const int* vi = ei;
    const int* hi = ei + NNZ_E;
    const float* W1 = (const float*)d_in[3];
    const float* b1 = (const float*)d_in[4];
    const float* W2 = (const float*)d_in[5];
    const float* b2 = (const float*)d_in[6];
    const float* W3 = (const float*)d_in[7];
    const float* b3 = (const float*)d_in[8];
    float* out = (float*)d_out;

    char* p = (char*)d_ws;
    auto take = [&](size_t bytes) -> void* {
        void* r = (void*)p;
        p += (bytes + 255) & ~(size_t)255;
        return r;
    };
    const int NB = (NN + 255) / 256;
    int* counts_v = (int*)take(NN * 4);
    int* counts_e = (int*)take(NE * 4);
    int* offs_v   = (int*)take(NN * 4);
    int* offs_e   = (int*)take(NE * 4);
    int* bsum_v   = (int*)take(NB * 4);
    int* bsum_e   = (int*)take(NB * 4);
    int* bbase_v  = (int*)take(NB * 4);
    int* bbase_e  = (int*)take(NB * 4);
    int* bcur_e   = (int*)take(NBUCK * 4);
    int* bcur_v   = (int*)take(NBUCK * 4);
    unsigned int* tmp_e = (unsigned int*)take((size_t)NBUCK * BCAP * 4);
    unsigned int* tmp_v = (unsigned int*)take((size_t)NBUCK * BCAP * 4);
    int* pay_v    = (int*)take((size_t)NNZ_E * 4);
    int* pay_e    = (int*)take((size_t)NNZ_E * 4);
    float* inv_v  = (float*)take(NN * 4);
    float* inv_e  = (float*)take(NE * 4);
    half_t* msgH  = (half_t*)take((size_t)NN * 256 * 2);
    half_t* xeH   = (half_t*)take((size_t)NE * 256 * 2);
    half_t* hA_h  = (half_t*)take((size_t)NN * 256 * 2);
    half_t* hA_l  = (half_t*)take((size_t)NN * 256 * 2);
    half_t* w1h   = (half_t*)take(256 * 256 * 2);
    half_t* w1l   = (half_t*)take(256 * 256 * 2);
    half_t* w2h   = (half_t*)take(256 * 256 * 2);
    half_t* w2l   = (half_t*)take(256 * 256 * 2);
    half_t* w3h   = (half_t*)take(256 * 128 * 2);
    half_t* w3l   = (half_t*)take(256 * 128 * 2);

    // ---- CSR build (bucket-binned, no random global scatter) ----
    hipMemsetAsync(bcur_e, 0, NBUCK * 4, stream);
    hipMemsetAsync(bcur_v, 0, NBUCK * 4, stream);
    bin_kernel<<<(NNZ_E + EPB - 1) / EPB, 256, 0, stream>>>(vi, hi, bcur_e, bcur_v, tmp_e, tmp_v);
    fine_count<<<NBUCK, 256, 0, stream>>>(bcur_e, tmp_e, counts_e, NE);
    fine_count<<<NBUCK, 256, 0, stream>>>(bcur_v, tmp_v, counts_v, NN);
    scan_blk<<<NB, 256, 0, stream>>>(counts_v, offs_v, bsum_v, NN);
    scan_blk<<<NB, 256, 0, stream>>>(counts_e, offs_e, bsum_e, NE);
    scan_top<<<1, 256, 0, stream>>>(bsum_v, bbase_v, NB);
    scan_top<<<1, 256, 0, stream>>>(bsum_e, bbase_e, NB);
    scan_fix<<<NB, 256, 0, stream>>>(counts_v, bbase_v, offs_v, inv_v, NN);
    scan_fix<<<NB, 256, 0, stream>>>(counts_e, bbase_e, offs_e, inv_e, NE);
    fine_scatter<<<NBUCK, 256, 0, stream>>>(bcur_e, tmp_e, offs_e, pay_e, NE);
    fine_scatter<<<NBUCK, 256, 0, stream>>>(bcur_v, tmp_v, offs_v, pay_v, NN);

    // ---- conversions ----
    cvt_split<<<(NN * 256 / 4 + 255) / 256, 256, 0, stream>>>(x, hA_h, hA_l, NN * 256);
    cvt_w<<<(256 * 256 + 255) / 256, 256, 0, stream>>>(W1, w1h, w1l, 256, 256);
    cvt_w<<<(256 * 256 + 255) / 256, 256, 0, stream>>>(W2, w2h, w2l, 256, 256);
    cvt_w<<<(256 * 128 + 255) / 256, 256, 0, stream>>>(W3, w3h, w3l, 256, 128);

    dim3 g256(2, (NN + 127) / 128);
    dim3 g128(1, (NN + 127) / 128);
    int gridC256 = (NN * 32 + 255) / 256;  // LPR=32
    int gridC128 = (NN * 16 + 255) / 256;  // LPR=16

    // ---- layer 1 ----
    gemm_hsplit<<<g256, 256, 0, stream>>>(hA_h, hA_l, w1h, w1l, msgH, NN, 256, 256);
    seg16<32, 0><<<gridC256, 256, 0, stream>>>(msgH, offs_e, counts_e, pay_e, inv_e,
                                               nullptr, xeH, nullptr, nullptr, NE);
    seg16<32, 1><<<gridC256, 256, 0, stream>>>(xeH, offs_v, counts_v, pay_v, inv_v,
                                               b1, hA_h, hA_l, nullptr, NN);
    // ---- layer 2 ----
    gemm_hsplit<<<g256, 256, 0, stream>>>(hA_h, hA_l, w2h, w2l, msgH, NN, 256, 256);
    seg16<32, 0><<<gridC256, 256, 0, stream>>>(msgH, offs_e, counts_e, pay_e, inv_e,
                                               nullptr, xeH, nullptr, nullptr, NE);
    seg16<32, 1><<<gridC256, 256, 0, stream>>>(xeH, offs_v, counts_v, pay_v, inv_v,
                                               b2, hA_h, hA_l, nullptr, NN);
    // ---- layer 3 (C=128, no activation) ----
    gemm_hsplit<<<g128, 256, 0, stream>>>(hA_h, hA_l, w3h, w3l, msgH, NN, 128, 256);
    seg16<16, 0><<<gridC128, 256, 0, stream>>>(msgH, offs_e, counts_e, pay_e, inv_e,
                                               nullptr, xeH, nullptr, nullptr, NE);
    seg16<16, 2><<<gridC128, 256, 0, stream>>>(xeH, offs_v, counts_v, pay_v, inv_v,
                                               b3, nullptr, nullptr, out, NN);
}